// Round 2
// baseline (20224.194 us; speedup 1.0000x reference)
//
#include <hip/hip_runtime.h>
#include <hip/hip_bf16.h>
#include <cstdint>
#include <cstddef>

// ---------------------------------------------------------------------------
// DVAE forward, fp32 baseline v2.
// Crash fix: workspace use capped at 64 MB (two 32 MB ping-pong buffers,
// decoder runs per-batch). Latent/threshold scratch lives in d_out's rec
// region (dead before rec is written). Weight LDS tile transposed to
// [ci][k][co] + float4 uniform reads so the conv inner loop is FMA-bound.
// Outputs concat: rec[8,3,256,256] routed[8,4,32,32] grain[8,16,16] ent[8,16,16]
// ---------------------------------------------------------------------------

#define B 8

// ---------------- encoder strided conv (Cin=3, Cout=4, k=3, pad=1) ----------
__global__ void enc_conv_kernel(const float* __restrict__ x, const float* __restrict__ w,
                                const float* __restrict__ bias, float* __restrict__ out,
                                int S, int HO) {
    int id = blockIdx.x * 256 + threadIdx.x;
    int total = B * 4 * HO * HO;
    if (id >= total) return;
    int ox = id % HO, oy = (id / HO) % HO, co = (id / (HO * HO)) % 4, b = id / (HO * HO * 4);
    float acc = bias[co];
    for (int ci = 0; ci < 3; ++ci) {
        const float* xp = x + ((size_t)b * 3 + ci) * 65536;
        const float* wp = w + (co * 3 + ci) * 9;
        #pragma unroll
        for (int ky = 0; ky < 3; ++ky) {
            int iy = oy * S - 1 + ky;
            if (iy < 0 || iy >= 256) continue;
            #pragma unroll
            for (int kx = 0; kx < 3; ++kx) {
                int ix = ox * S - 1 + kx;
                if (ix < 0 || ix >= 256) continue;
                acc = fmaf(xp[iy * 256 + ix], wp[ky * 3 + kx], acc);
            }
        }
    }
    out[id] = acc;
}

// ---------------- entropy (KDE), gray fused ----------------
// one block per 16x16 patch; 256 threads = 256 bins
__global__ __launch_bounds__(256) void entropy_kernel(const float* __restrict__ x,
                                                      float* __restrict__ ent) {
    __shared__ float s_patch[256];
    __shared__ float s_red[4];
    int blk = blockIdx.x;                 // b*256 + py*16 + px
    int b = blk >> 8, rem = blk & 255;
    int py = rem >> 4, px = rem & 15;
    int tid = threadIdx.x;
    int pr = tid >> 4, pc = tid & 15;
    const float* xb = x + (size_t)b * 3 * 65536;
    int p = (py * 16 + pr) * 256 + (px * 16 + pc);
    s_patch[tid] = 0.299f * xb[p] + 0.587f * xb[65536 + p] + 0.114f * xb[2 * 65536 + p];
    __syncthreads();

    float bin = (float)tid * (1.0f / 255.0f);
    float s = 0.f;
    #pragma unroll 8
    for (int q = 0; q < 256; ++q) {
        float t = (s_patch[q] - bin) * 100.0f;
        s += expf(-0.5f * (t * t));
    }
    float pdf = s * (1.0f / 256.0f);

    float r = pdf;
    #pragma unroll
    for (int o = 32; o > 0; o >>= 1) r += __shfl_down(r, o, 64);
    if ((tid & 63) == 0) s_red[tid >> 6] = r;
    __syncthreads();
    float total = s_red[0] + s_red[1] + s_red[2] + s_red[3];
    __syncthreads();

    float p2 = pdf / total;
    p2 = fmaxf(p2, 1e-10f);
    float e = -p2 * log2f(p2);
    #pragma unroll
    for (int o = 32; o > 0; o >>= 1) e += __shfl_down(e, o, 64);
    if ((tid & 63) == 0) s_red[tid >> 6] = e;
    __syncthreads();
    if (tid == 0) ent[blk] = s_red[0] + s_red[1] + s_red[2] + s_red[3];
}

// ---------------- median of 2048 values (bitonic sort) ----------------
__global__ __launch_bounds__(1024) void median_kernel(const float* __restrict__ ent,
                                                      float* __restrict__ thr) {
    __shared__ float s[2048];
    int tid = threadIdx.x;
    s[tid] = ent[tid];
    s[tid + 1024] = ent[tid + 1024];
    __syncthreads();
    for (int k = 2; k <= 2048; k <<= 1) {
        for (int j = k >> 1; j > 0; j >>= 1) {
            int t = tid;
            #pragma unroll 1
            for (int rep = 0; rep < 2; ++rep, t += 1024) {
                int ixj = t ^ j;
                if (ixj > t) {
                    float a = s[t], bb = s[ixj];
                    bool up = ((t & k) == 0);
                    bool sw = up ? (a > bb) : (a < bb);
                    if (sw) { s[t] = bb; s[ixj] = a; }
                }
            }
            __syncthreads();
        }
    }
    if (tid == 0) *thr = 0.5f * (s[1023] + s[1024]);
}

// ---------------- grain ----------------
__global__ void grain_kernel(const float* __restrict__ ent, const float* __restrict__ thr,
                             float* __restrict__ grain) {
    int id = blockIdx.x * 256 + threadIdx.x;
    if (id >= 2048) return;
    grain[id] = (ent[id] > *thr) ? 1.0f : 0.0f;
}

// ---------------- routing ----------------
__global__ void route_kernel(const float* __restrict__ latf, const float* __restrict__ latc,
                             const float* __restrict__ grain, float* __restrict__ routed) {
    int id = blockIdx.x * 256 + threadIdx.x;            // [8,4,32,32]
    if (id >= B * 4 * 32 * 32) return;
    int xx = id & 31, yy = (id >> 5) & 31, c = (id >> 10) & 3, b = id >> 12;
    float g = grain[b * 256 + (yy >> 1) * 16 + (xx >> 1)];
    float cu = latc[((b * 4 + c) * 16 + (yy >> 1)) * 16 + (xx >> 1)];
    routed[id] = g * latf[id] + (1.0f - g) * cu;
}

// ---------------- conv 3x3, pad 1, stride 1 (single batch) ----------------
// block 256 threads = 16x16 spatial tile; CO_BLK output channels per block.
// grid: (COUT/CO_BLK ceil, tiles, 1). Weight LDS transposed [ci][k][co].
template<int CIN, int COUT, int H, int W, int CI_BLK, int CO_BLK, int ACT>
__global__ __launch_bounds__(256) void conv3x3(const float* __restrict__ in,
                                               const float* __restrict__ wgt,
                                               const float* __restrict__ bias,
                                               float* __restrict__ out) {
    constexpr int TW = W / 16;
    __shared__ float s_in[CI_BLK][18][18];
    __shared__ float s_w[CI_BLK][9][CO_BLK];
    const int tid = threadIdx.x;
    const int lx = tid & 15, ly = tid >> 4;
    const int co0 = blockIdx.x * CO_BLK;
    const int tile = blockIdx.y;
    const int tx0 = (tile % TW) * 16, ty0 = (tile / TW) * 16;
    const int ox = tx0 + lx, oy = ty0 + ly;

    float acc[CO_BLK];
    #pragma unroll
    for (int i = 0; i < CO_BLK; ++i) acc[i] = bias[co0 + i];

    for (int ci0 = 0; ci0 < CIN; ci0 += CI_BLK) {
        for (int idx = tid; idx < CI_BLK * 324; idx += 256) {
            int ci = idx / 324, rm = idx % 324;
            int r = rm / 18, c = rm % 18;
            int iy = ty0 - 1 + r, ix = tx0 - 1 + c;
            float v = 0.f;
            if (iy >= 0 && iy < H && ix >= 0 && ix < W)
                v = in[((size_t)(ci0 + ci) * H + iy) * W + ix];
            s_in[ci][r][c] = v;
        }
        for (int idx = tid; idx < CI_BLK * 9 * CO_BLK; idx += 256) {
            int ci = idx / (9 * CO_BLK), rm = idx % (9 * CO_BLK);
            int k = rm / CO_BLK, co = rm % CO_BLK;
            s_w[ci][k][co] = wgt[((size_t)(co0 + co) * CIN + ci0 + ci) * 9 + k];
        }
        __syncthreads();
        #pragma unroll
        for (int ci = 0; ci < CI_BLK; ++ci) {
            float v[9];
            #pragma unroll
            for (int ky = 0; ky < 3; ++ky)
                #pragma unroll
                for (int kx = 0; kx < 3; ++kx)
                    v[ky * 3 + kx] = s_in[ci][ly + ky][lx + kx];
            if constexpr ((CO_BLK & 3) == 0) {
                #pragma unroll
                for (int k = 0; k < 9; ++k) {
                    #pragma unroll
                    for (int c4 = 0; c4 < CO_BLK / 4; ++c4) {
                        const float4 w4 = *reinterpret_cast<const float4*>(&s_w[ci][k][c4 * 4]);
                        acc[c4 * 4 + 0] = fmaf(v[k], w4.x, acc[c4 * 4 + 0]);
                        acc[c4 * 4 + 1] = fmaf(v[k], w4.y, acc[c4 * 4 + 1]);
                        acc[c4 * 4 + 2] = fmaf(v[k], w4.z, acc[c4 * 4 + 2]);
                        acc[c4 * 4 + 3] = fmaf(v[k], w4.w, acc[c4 * 4 + 3]);
                    }
                }
            } else {
                #pragma unroll
                for (int k = 0; k < 9; ++k)
                    #pragma unroll
                    for (int co = 0; co < CO_BLK; ++co)
                        acc[co] = fmaf(v[k], s_w[ci][k][co], acc[co]);
            }
        }
        __syncthreads();
    }
    #pragma unroll
    for (int co = 0; co < CO_BLK; ++co) {
        float v = acc[co];
        if (ACT == 1) v = fmaxf(v, 0.f);
        if (ACT == 2) v = tanhf(v);
        out[((size_t)(co0 + co) * H + oy) * W + ox] = v;
    }
}

// ---------------- deconv (ConvTranspose2d k=3 s=2 p=1 op=1) + ReLU ---------
// gather form: out[oy,ox] = b + sum in[iy,ix]*w[ci,co,fy,fx], oy=2*iy-1+fy.
// single batch; weight LDS transposed [ci][k][co].
template<int CIN, int COUT, int HIN, int WIN, int CI_BLK, int CO_BLK>
__global__ __launch_bounds__(256) void deconv3x3(const float* __restrict__ in,
                                                 const float* __restrict__ wgt,
                                                 const float* __restrict__ bias,
                                                 float* __restrict__ out) {
    constexpr int HO = 2 * HIN, WO = 2 * WIN;
    constexpr int TW = WO / 16;
    __shared__ float s_in[CI_BLK][9][9];
    __shared__ float s_w[CI_BLK][9][CO_BLK];
    const int tid = threadIdx.x;
    const int lx = tid & 15, ly = tid >> 4;
    const int co0 = blockIdx.x * CO_BLK;
    const int tile = blockIdx.y;
    const int tx0 = (tile % TW) * 16, ty0 = (tile / TW) * 16;
    const int oy = ty0 + ly, ox = tx0 + lx;
    const int iyb = ty0 >> 1, ixb = tx0 >> 1;

    int syi[2], syf[2]; bool syv[2];
    if ((oy & 1) == 0) {
        syi[0] = (oy >> 1) - iyb; syf[0] = 1; syv[0] = true;
        syi[1] = 0; syf[1] = 0; syv[1] = false;
    } else {
        syi[0] = ((oy + 1) >> 1) - iyb; syf[0] = 0; syv[0] = ((oy + 1) >> 1) < HIN;
        syi[1] = ((oy - 1) >> 1) - iyb; syf[1] = 2; syv[1] = true;
    }
    int sxi[2], sxf[2]; bool sxv[2];
    if ((ox & 1) == 0) {
        sxi[0] = (ox >> 1) - ixb; sxf[0] = 1; sxv[0] = true;
        sxi[1] = 0; sxf[1] = 0; sxv[1] = false;
    } else {
        sxi[0] = ((ox + 1) >> 1) - ixb; sxf[0] = 0; sxv[0] = ((ox + 1) >> 1) < WIN;
        sxi[1] = ((ox - 1) >> 1) - ixb; sxf[1] = 2; sxv[1] = true;
    }

    float acc[CO_BLK];
    #pragma unroll
    for (int i = 0; i < CO_BLK; ++i) acc[i] = bias[co0 + i];

    for (int ci0 = 0; ci0 < CIN; ci0 += CI_BLK) {
        for (int idx = tid; idx < CI_BLK * 81; idx += 256) {
            int ci = idx / 81, rm = idx % 81;
            int r = rm / 9, c = rm % 9;
            int iy = iyb + r, ix = ixb + c;
            float v = 0.f;
            if (iy < HIN && ix < WIN)
                v = in[((size_t)(ci0 + ci) * HIN + iy) * WIN + ix];
            s_in[ci][r][c] = v;
        }
        for (int idx = tid; idx < CI_BLK * 9 * CO_BLK; idx += 256) {
            int ci = idx / (9 * CO_BLK), rm = idx % (9 * CO_BLK);
            int k = rm / CO_BLK, co = rm % CO_BLK;
            s_w[ci][k][co] = wgt[((size_t)(ci0 + ci) * COUT + co0 + co) * 9 + k];
        }
        __syncthreads();
        #pragma unroll
        for (int ci = 0; ci < CI_BLK; ++ci) {
            #pragma unroll
            for (int sy = 0; sy < 2; ++sy) {
                #pragma unroll
                for (int sx = 0; sx < 2; ++sx) {
                    float v = (syv[sy] && sxv[sx]) ? s_in[ci][syi[sy]][sxi[sx]] : 0.f;
                    int k = syf[sy] * 3 + sxf[sx];
                    #pragma unroll
                    for (int c4 = 0; c4 < CO_BLK / 4; ++c4) {
                        const float4 w4 = *reinterpret_cast<const float4*>(&s_w[ci][k][c4 * 4]);
                        acc[c4 * 4 + 0] = fmaf(v, w4.x, acc[c4 * 4 + 0]);
                        acc[c4 * 4 + 1] = fmaf(v, w4.y, acc[c4 * 4 + 1]);
                        acc[c4 * 4 + 2] = fmaf(v, w4.z, acc[c4 * 4 + 2]);
                        acc[c4 * 4 + 3] = fmaf(v, w4.w, acc[c4 * 4 + 3]);
                    }
                }
            }
        }
        __syncthreads();
    }
    #pragma unroll
    for (int co = 0; co < CO_BLK; ++co)
        out[((size_t)(co0 + co) * HO + oy) * WO + ox] = fmaxf(acc[co], 0.f);
}

// ---------------------------------------------------------------------------
extern "C" void kernel_launch(void* const* d_in, const int* in_sizes, int n_in,
                              void* d_out, int out_size, void* d_ws, size_t ws_size,
                              hipStream_t stream) {
    const float* x   = (const float*)d_in[0];
    const float* We0 = (const float*)d_in[1];  const float* be0 = (const float*)d_in[2];
    const float* We1 = (const float*)d_in[3];  const float* be1 = (const float*)d_in[4];
    const float* Wi  = (const float*)d_in[5];  const float* bi  = (const float*)d_in[6];
    const float* Wd1 = (const float*)d_in[7];  const float* bd1 = (const float*)d_in[8];
    const float* Wc1 = (const float*)d_in[9];  const float* bc1 = (const float*)d_in[10];
    const float* Wd2 = (const float*)d_in[11]; const float* bd2 = (const float*)d_in[12];
    const float* Wc2 = (const float*)d_in[13]; const float* bc2 = (const float*)d_in[14];
    const float* Wd3 = (const float*)d_in[15]; const float* bd3 = (const float*)d_in[16];
    const float* Wc3 = (const float*)d_in[17]; const float* bc3 = (const float*)d_in[18];
    const float* Wo  = (const float*)d_in[19]; const float* bo  = (const float*)d_in[20];

    float* out    = (float*)d_out;
    float* rec    = out;               // [8,3,256,256]
    float* routed = out + 1572864;     // [8,4,32,32]
    float* grain  = out + 1605632;     // [8,16,16]
    float* ent    = out + 1607680;     // [8,16,16]

    // latent scratch lives in rec's region: dead before first rec write
    // (routing finishes before the decoder starts; stream-serial).
    float* latf = out;                 // 32768 floats
    float* latc = out + 32768;         // 8192 floats
    float* thr  = out + 40960;         // 1 float

    // workspace: exactly 64 MB — two 32 MB ping-pong buffers
    char* ws = (char*)d_ws;
    float* U = (float*)(ws);
    float* V = (float*)(ws + (size_t)32 * 1024 * 1024);

    // --- entropy / routing path ---
    enc_conv_kernel<<<128, 256, 0, stream>>>(x, We0, be0, latf, 8, 32);
    enc_conv_kernel<<<32, 256, 0, stream>>>(x, We1, be1, latc, 16, 16);
    entropy_kernel<<<2048, 256, 0, stream>>>(x, ent);
    median_kernel<<<1, 1024, 0, stream>>>(ent, thr);
    grain_kernel<<<8, 256, 0, stream>>>(ent, thr, grain);
    route_kernel<<<128, 256, 0, stream>>>(latf, latc, grain, routed);

    // --- decoder, per batch (ping-pong U/V, each 32 MB) ---
    for (int b = 0; b < B; ++b) {
        const float* rb = routed + (size_t)b * 4 * 32 * 32;
        float* recb = rec + (size_t)b * 3 * 65536;
        conv3x3<4, 256, 32, 32, 4, 16, 0><<<dim3(16, 4, 1), 256, 0, stream>>>(rb, Wi, bi, U);
        deconv3x3<256, 256, 32, 32, 8, 16><<<dim3(16, 16, 1), 256, 0, stream>>>(U, Wd1, bd1, V);
        conv3x3<256, 256, 64, 64, 8, 16, 1><<<dim3(16, 16, 1), 256, 0, stream>>>(V, Wc1, bc1, U);
        deconv3x3<256, 128, 64, 64, 8, 16><<<dim3(8, 64, 1), 256, 0, stream>>>(U, Wd2, bd2, V);
        conv3x3<128, 128, 128, 128, 8, 16, 1><<<dim3(8, 64, 1), 256, 0, stream>>>(V, Wc2, bc2, U);
        deconv3x3<128, 128, 128, 128, 8, 16><<<dim3(8, 256, 1), 256, 0, stream>>>(U, Wd3, bd3, V);
        conv3x3<128, 128, 256, 256, 8, 16, 1><<<dim3(8, 256, 1), 256, 0, stream>>>(V, Wc3, bc3, U);
        conv3x3<128, 3, 256, 256, 8, 3, 2><<<dim3(1, 256, 1), 256, 0, stream>>>(U, Wo, bo, recb);
    }
}

// Round 3
// 11696.866 us; speedup vs baseline: 1.7290x; 1.7290x over previous
//
#include <hip/hip_runtime.h>
#include <hip/hip_bf16.h>
#include <cstdint>
#include <cstddef>

// ---------------------------------------------------------------------------
// DVAE forward, fp32 v3.
// Round-2 fix: deconv rewritten as parity-split quad kernel. The old gather
// deconv spilled (VGPR=256, 1.4 GB scratch writes/dispatch, 17% VALUBusy).
// Each thread now computes a 2x2 output quad x CO_BLK couts: 9 FMAs per
// (ci, cout) with every weight used exactly once (no masked taps), ~100 VGPR,
// float2-coalesced stores.
// Outputs concat: rec[8,3,256,256] routed[8,4,32,32] grain[8,16,16] ent[8,16,16]
// ---------------------------------------------------------------------------

#define B 8

// ---------------- encoder strided conv (Cin=3, Cout=4, k=3, pad=1) ----------
__global__ void enc_conv_kernel(const float* __restrict__ x, const float* __restrict__ w,
                                const float* __restrict__ bias, float* __restrict__ out,
                                int S, int HO) {
    int id = blockIdx.x * 256 + threadIdx.x;
    int total = B * 4 * HO * HO;
    if (id >= total) return;
    int ox = id % HO, oy = (id / HO) % HO, co = (id / (HO * HO)) % 4, b = id / (HO * HO * 4);
    float acc = bias[co];
    for (int ci = 0; ci < 3; ++ci) {
        const float* xp = x + ((size_t)b * 3 + ci) * 65536;
        const float* wp = w + (co * 3 + ci) * 9;
        #pragma unroll
        for (int ky = 0; ky < 3; ++ky) {
            int iy = oy * S - 1 + ky;
            if (iy < 0 || iy >= 256) continue;
            #pragma unroll
            for (int kx = 0; kx < 3; ++kx) {
                int ix = ox * S - 1 + kx;
                if (ix < 0 || ix >= 256) continue;
                acc = fmaf(xp[iy * 256 + ix], wp[ky * 3 + kx], acc);
            }
        }
    }
    out[id] = acc;
}

// ---------------- entropy (KDE), gray fused ----------------
__global__ __launch_bounds__(256) void entropy_kernel(const float* __restrict__ x,
                                                      float* __restrict__ ent) {
    __shared__ float s_patch[256];
    __shared__ float s_red[4];
    int blk = blockIdx.x;                 // b*256 + py*16 + px
    int b = blk >> 8, rem = blk & 255;
    int py = rem >> 4, px = rem & 15;
    int tid = threadIdx.x;
    int pr = tid >> 4, pc = tid & 15;
    const float* xb = x + (size_t)b * 3 * 65536;
    int p = (py * 16 + pr) * 256 + (px * 16 + pc);
    s_patch[tid] = 0.299f * xb[p] + 0.587f * xb[65536 + p] + 0.114f * xb[2 * 65536 + p];
    __syncthreads();

    float bin = (float)tid * (1.0f / 255.0f);
    float s = 0.f;
    #pragma unroll 8
    for (int q = 0; q < 256; ++q) {
        float t = (s_patch[q] - bin) * 100.0f;
        s += expf(-0.5f * (t * t));
    }
    float pdf = s * (1.0f / 256.0f);

    float r = pdf;
    #pragma unroll
    for (int o = 32; o > 0; o >>= 1) r += __shfl_down(r, o, 64);
    if ((tid & 63) == 0) s_red[tid >> 6] = r;
    __syncthreads();
    float total = s_red[0] + s_red[1] + s_red[2] + s_red[3];
    __syncthreads();

    float p2 = pdf / total;
    p2 = fmaxf(p2, 1e-10f);
    float e = -p2 * log2f(p2);
    #pragma unroll
    for (int o = 32; o > 0; o >>= 1) e += __shfl_down(e, o, 64);
    if ((tid & 63) == 0) s_red[tid >> 6] = e;
    __syncthreads();
    if (tid == 0) ent[blk] = s_red[0] + s_red[1] + s_red[2] + s_red[3];
}

// ---------------- median of 2048 values (bitonic sort) ----------------
__global__ __launch_bounds__(1024) void median_kernel(const float* __restrict__ ent,
                                                      float* __restrict__ thr) {
    __shared__ float s[2048];
    int tid = threadIdx.x;
    s[tid] = ent[tid];
    s[tid + 1024] = ent[tid + 1024];
    __syncthreads();
    for (int k = 2; k <= 2048; k <<= 1) {
        for (int j = k >> 1; j > 0; j >>= 1) {
            int t = tid;
            #pragma unroll 1
            for (int rep = 0; rep < 2; ++rep, t += 1024) {
                int ixj = t ^ j;
                if (ixj > t) {
                    float a = s[t], bb = s[ixj];
                    bool up = ((t & k) == 0);
                    bool sw = up ? (a > bb) : (a < bb);
                    if (sw) { s[t] = bb; s[ixj] = a; }
                }
            }
            __syncthreads();
        }
    }
    if (tid == 0) *thr = 0.5f * (s[1023] + s[1024]);
}

// ---------------- grain ----------------
__global__ void grain_kernel(const float* __restrict__ ent, const float* __restrict__ thr,
                             float* __restrict__ grain) {
    int id = blockIdx.x * 256 + threadIdx.x;
    if (id >= 2048) return;
    grain[id] = (ent[id] > *thr) ? 1.0f : 0.0f;
}

// ---------------- routing ----------------
__global__ void route_kernel(const float* __restrict__ latf, const float* __restrict__ latc,
                             const float* __restrict__ grain, float* __restrict__ routed) {
    int id = blockIdx.x * 256 + threadIdx.x;            // [8,4,32,32]
    if (id >= B * 4 * 32 * 32) return;
    int xx = id & 31, yy = (id >> 5) & 31, c = (id >> 10) & 3, b = id >> 12;
    float g = grain[b * 256 + (yy >> 1) * 16 + (xx >> 1)];
    float cu = latc[((b * 4 + c) * 16 + (yy >> 1)) * 16 + (xx >> 1)];
    routed[id] = g * latf[id] + (1.0f - g) * cu;
}

// ---------------- conv 3x3, pad 1, stride 1 (single batch) ----------------
template<int CIN, int COUT, int H, int W, int CI_BLK, int CO_BLK, int ACT>
__global__ __launch_bounds__(256) void conv3x3(const float* __restrict__ in,
                                               const float* __restrict__ wgt,
                                               const float* __restrict__ bias,
                                               float* __restrict__ out) {
    constexpr int TW = W / 16;
    __shared__ float s_in[CI_BLK][18][18];
    __shared__ float s_w[CI_BLK][9][CO_BLK];
    const int tid = threadIdx.x;
    const int lx = tid & 15, ly = tid >> 4;
    const int co0 = blockIdx.x * CO_BLK;
    const int tile = blockIdx.y;
    const int tx0 = (tile % TW) * 16, ty0 = (tile / TW) * 16;
    const int ox = tx0 + lx, oy = ty0 + ly;

    float acc[CO_BLK];
    #pragma unroll
    for (int i = 0; i < CO_BLK; ++i) acc[i] = bias[co0 + i];

    for (int ci0 = 0; ci0 < CIN; ci0 += CI_BLK) {
        for (int idx = tid; idx < CI_BLK * 324; idx += 256) {
            int ci = idx / 324, rm = idx % 324;
            int r = rm / 18, c = rm % 18;
            int iy = ty0 - 1 + r, ix = tx0 - 1 + c;
            float v = 0.f;
            if (iy >= 0 && iy < H && ix >= 0 && ix < W)
                v = in[((size_t)(ci0 + ci) * H + iy) * W + ix];
            s_in[ci][r][c] = v;
        }
        for (int idx = tid; idx < CI_BLK * 9 * CO_BLK; idx += 256) {
            int ci = idx / (9 * CO_BLK), rm = idx % (9 * CO_BLK);
            int k = rm / CO_BLK, co = rm % CO_BLK;
            s_w[ci][k][co] = wgt[((size_t)(co0 + co) * CIN + ci0 + ci) * 9 + k];
        }
        __syncthreads();
        #pragma unroll
        for (int ci = 0; ci < CI_BLK; ++ci) {
            float v[9];
            #pragma unroll
            for (int ky = 0; ky < 3; ++ky)
                #pragma unroll
                for (int kx = 0; kx < 3; ++kx)
                    v[ky * 3 + kx] = s_in[ci][ly + ky][lx + kx];
            if constexpr ((CO_BLK & 3) == 0) {
                #pragma unroll
                for (int k = 0; k < 9; ++k) {
                    #pragma unroll
                    for (int c4 = 0; c4 < CO_BLK / 4; ++c4) {
                        const float4 w4 = *reinterpret_cast<const float4*>(&s_w[ci][k][c4 * 4]);
                        acc[c4 * 4 + 0] = fmaf(v[k], w4.x, acc[c4 * 4 + 0]);
                        acc[c4 * 4 + 1] = fmaf(v[k], w4.y, acc[c4 * 4 + 1]);
                        acc[c4 * 4 + 2] = fmaf(v[k], w4.z, acc[c4 * 4 + 2]);
                        acc[c4 * 4 + 3] = fmaf(v[k], w4.w, acc[c4 * 4 + 3]);
                    }
                }
            } else {
                #pragma unroll
                for (int k = 0; k < 9; ++k)
                    #pragma unroll
                    for (int co = 0; co < CO_BLK; ++co)
                        acc[co] = fmaf(v[k], s_w[ci][k][co], acc[co]);
            }
        }
        __syncthreads();
    }
    #pragma unroll
    for (int co = 0; co < CO_BLK; ++co) {
        float v = acc[co];
        if (ACT == 1) v = fmaxf(v, 0.f);
        if (ACT == 2) v = tanhf(v);
        out[((size_t)(co0 + co) * H + oy) * W + ox] = v;
    }
}

// ---------------- deconv (ConvTranspose2d k=3 s=2 p=1 op=1) + ReLU ---------
// Parity-split: each thread computes the 2x2 output quad (2r,2c)..(2r+1,2c+1)
// for CO_BLK couts. Derivation (verified against round-2 passing gather form,
// oy = 2*iy - 1 + fy):
//   ee(2r,2c)     = i00*w[1][1]
//   eo(2r,2c+1)   = i00*w[1][2] + i01*w[1][0]
//   oe(2r+1,2c)   = i00*w[2][1] + i10*w[0][1]
//   oo(2r+1,2c+1) = i00*w[2][2] + i01*w[2][0] + i10*w[0][2] + i11*w[0][0]
// where i00=in[r][c], i01=in[r][c+1], i10=in[r+1][c], i11=in[r+1][c+1].
// 9 FMAs per (ci,cout) — every weight used exactly once, no masked work.
template<int CIN, int COUT, int HIN, int WIN, int CI_BLK, int CO_BLK>
__global__ __launch_bounds__(256) void deconvP(const float* __restrict__ in,
                                               const float* __restrict__ wgt,
                                               const float* __restrict__ bias,
                                               float* __restrict__ out) {
    constexpr int HO = 2 * HIN, WO = 2 * WIN;
    constexpr int QTW = WIN / 16;                  // quad-tiles across
    __shared__ float s_in[CI_BLK][17][18];
    __shared__ float s_w[CI_BLK][9][CO_BLK];
    const int tid = threadIdx.x;
    const int qx = tid & 15, qy = tid >> 4;        // quad coords in tile
    const int co0 = blockIdx.x * CO_BLK;
    const int tile = blockIdx.y;
    const int c0 = (tile % QTW) * 16, r0 = (tile / QTW) * 16;   // input coords
    const int r = r0 + qy, c = c0 + qx;

    float acc[4][CO_BLK];                          // 0=ee 1=eo 2=oe 3=oo
    #pragma unroll
    for (int p = 0; p < 4; ++p)
        #pragma unroll
        for (int i = 0; i < CO_BLK; ++i) acc[p][i] = 0.f;

    for (int ci0 = 0; ci0 < CIN; ci0 += CI_BLK) {
        for (int idx = tid; idx < CI_BLK * 17 * 18; idx += 256) {
            int ci = idx / (17 * 18), rm = idx % (17 * 18);
            int rr = rm / 18, cc = rm % 18;
            int iy = r0 + rr, ix = c0 + cc;
            float v = 0.f;
            if (cc < 17 && iy < HIN && ix < WIN)
                v = in[((size_t)(ci0 + ci) * HIN + iy) * WIN + ix];
            s_in[ci][rr][cc] = v;
        }
        for (int idx = tid; idx < CI_BLK * 9 * CO_BLK; idx += 256) {
            int ci = idx / (9 * CO_BLK), rm = idx % (9 * CO_BLK);
            int k = rm / CO_BLK, co = rm % CO_BLK;
            s_w[ci][k][co] = wgt[((size_t)(ci0 + ci) * COUT + co0 + co) * 9 + k];
        }
        __syncthreads();
        #pragma unroll
        for (int ci = 0; ci < CI_BLK; ++ci) {
            const float iv[4] = { s_in[ci][qy][qx],     s_in[ci][qy][qx + 1],
                                  s_in[ci][qy + 1][qx], s_in[ci][qy + 1][qx + 1] };
            #pragma unroll
            for (int k = 0; k < 9; ++k) {
                constexpr int SRC[9] = {3, 2, 2, 1, 0, 0, 1, 0, 0};
                constexpr int DST[9] = {3, 2, 3, 1, 0, 1, 3, 2, 3};
                #pragma unroll
                for (int c4 = 0; c4 < CO_BLK / 4; ++c4) {
                    const float4 w4 = *reinterpret_cast<const float4*>(&s_w[ci][k][c4 * 4]);
                    acc[DST[k]][c4 * 4 + 0] = fmaf(iv[SRC[k]], w4.x, acc[DST[k]][c4 * 4 + 0]);
                    acc[DST[k]][c4 * 4 + 1] = fmaf(iv[SRC[k]], w4.y, acc[DST[k]][c4 * 4 + 1]);
                    acc[DST[k]][c4 * 4 + 2] = fmaf(iv[SRC[k]], w4.z, acc[DST[k]][c4 * 4 + 2]);
                    acc[DST[k]][c4 * 4 + 3] = fmaf(iv[SRC[k]], w4.w, acc[DST[k]][c4 * 4 + 3]);
                }
            }
        }
        __syncthreads();
    }
    const int oy0 = 2 * r, ox0 = 2 * c;
    #pragma unroll
    for (int co = 0; co < CO_BLK; ++co) {
        const float bv = bias[co0 + co];
        float2 e, o;
        e.x = fmaxf(acc[0][co] + bv, 0.f);
        e.y = fmaxf(acc[1][co] + bv, 0.f);
        o.x = fmaxf(acc[2][co] + bv, 0.f);
        o.y = fmaxf(acc[3][co] + bv, 0.f);
        float* po = out + ((size_t)(co0 + co) * HO + oy0) * WO + ox0;
        *reinterpret_cast<float2*>(po) = e;
        *reinterpret_cast<float2*>(po + WO) = o;
    }
}

// ---------------------------------------------------------------------------
extern "C" void kernel_launch(void* const* d_in, const int* in_sizes, int n_in,
                              void* d_out, int out_size, void* d_ws, size_t ws_size,
                              hipStream_t stream) {
    const float* x   = (const float*)d_in[0];
    const float* We0 = (const float*)d_in[1];  const float* be0 = (const float*)d_in[2];
    const float* We1 = (const float*)d_in[3];  const float* be1 = (const float*)d_in[4];
    const float* Wi  = (const float*)d_in[5];  const float* bi  = (const float*)d_in[6];
    const float* Wd1 = (const float*)d_in[7];  const float* bd1 = (const float*)d_in[8];
    const float* Wc1 = (const float*)d_in[9];  const float* bc1 = (const float*)d_in[10];
    const float* Wd2 = (const float*)d_in[11]; const float* bd2 = (const float*)d_in[12];
    const float* Wc2 = (const float*)d_in[13]; const float* bc2 = (const float*)d_in[14];
    const float* Wd3 = (const float*)d_in[15]; const float* bd3 = (const float*)d_in[16];
    const float* Wc3 = (const float*)d_in[17]; const float* bc3 = (const float*)d_in[18];
    const float* Wo  = (const float*)d_in[19]; const float* bo  = (const float*)d_in[20];

    float* out    = (float*)d_out;
    float* rec    = out;               // [8,3,256,256]
    float* routed = out + 1572864;     // [8,4,32,32]
    float* grain  = out + 1605632;     // [8,16,16]
    float* ent    = out + 1607680;     // [8,16,16]

    // latent scratch in rec's region: dead before first rec write.
    float* latf = out;                 // 32768 floats
    float* latc = out + 32768;         // 8192 floats
    float* thr  = out + 40960;         // 1 float

    // workspace: 64 MB — two 32 MB ping-pong buffers
    char* ws = (char*)d_ws;
    float* U = (float*)(ws);
    float* V = (float*)(ws + (size_t)32 * 1024 * 1024);

    // --- entropy / routing path ---
    enc_conv_kernel<<<128, 256, 0, stream>>>(x, We0, be0, latf, 8, 32);
    enc_conv_kernel<<<32, 256, 0, stream>>>(x, We1, be1, latc, 16, 16);
    entropy_kernel<<<2048, 256, 0, stream>>>(x, ent);
    median_kernel<<<1, 1024, 0, stream>>>(ent, thr);
    grain_kernel<<<8, 256, 0, stream>>>(ent, thr, grain);
    route_kernel<<<128, 256, 0, stream>>>(latf, latc, grain, routed);

    // --- decoder, per batch (ping-pong U/V, each 32 MB) ---
    for (int b = 0; b < B; ++b) {
        const float* rb = routed + (size_t)b * 4 * 32 * 32;
        float* recb = rec + (size_t)b * 3 * 65536;
        conv3x3<4, 256, 32, 32, 4, 16, 0><<<dim3(16, 4, 1), 256, 0, stream>>>(rb, Wi, bi, U);
        deconvP<256, 256, 32, 32, 8, 4><<<dim3(64, 4, 1), 256, 0, stream>>>(U, Wd1, bd1, V);
        conv3x3<256, 256, 64, 64, 8, 16, 1><<<dim3(16, 16, 1), 256, 0, stream>>>(V, Wc1, bc1, U);
        deconvP<256, 128, 64, 64, 8, 8><<<dim3(16, 16, 1), 256, 0, stream>>>(U, Wd2, bd2, V);
        conv3x3<128, 128, 128, 128, 8, 16, 1><<<dim3(8, 64, 1), 256, 0, stream>>>(V, Wc2, bc2, U);
        deconvP<128, 128, 128, 128, 8, 8><<<dim3(16, 64, 1), 256, 0, stream>>>(U, Wd3, bd3, V);
        conv3x3<128, 128, 256, 256, 8, 16, 1><<<dim3(8, 256, 1), 256, 0, stream>>>(V, Wc3, bc3, U);
        conv3x3<128, 3, 256, 256, 8, 3, 2><<<dim3(1, 256, 1), 256, 0, stream>>>(U, Wo, bo, recb);
    }
}

// Round 4
// 6617.322 us; speedup vs baseline: 3.0563x; 1.7676x over previous
//
#include <hip/hip_runtime.h>
#include <hip/hip_bf16.h>
#include <cstdint>
#include <cstddef>

// ---------------------------------------------------------------------------
// DVAE forward v4: decoder convs c1/c2/c3 on MFMA (split-bf16 hi/lo, 3-term).
// deconvs now write bf16 hi/lo planes in [y][x][c]; convM consumes them and
// writes fp32 planar for the next deconv / final conv. Weights pre-split per
// stage into rotating dead-region slots (U+16MB, V+24MB, rec[7] tail).
// ws usage stays exactly 64 MB (U 32MB | V 32MB).
// ---------------------------------------------------------------------------

#define B 8

typedef __attribute__((ext_vector_type(8)))  short  short8;
typedef __attribute__((ext_vector_type(4)))  short  short4v;
typedef __attribute__((ext_vector_type(16))) float  f32x16;

__device__ inline unsigned short f2bf(float x) {          // RNE f32->bf16
    uint32_t u = __float_as_uint(x);
    uint32_t r = (u + 0x7FFFu + ((u >> 16) & 1u)) >> 16;
    return (unsigned short)r;
}
__device__ inline float bf2f(unsigned short h) {
    return __uint_as_float(((uint32_t)h) << 16);
}

// ---------------- encoder strided conv (Cin=3, Cout=4, k=3, pad=1) ----------
__global__ void enc_conv_kernel(const float* __restrict__ x, const float* __restrict__ w,
                                const float* __restrict__ bias, float* __restrict__ out,
                                int S, int HO) {
    int id = blockIdx.x * 256 + threadIdx.x;
    int total = B * 4 * HO * HO;
    if (id >= total) return;
    int ox = id % HO, oy = (id / HO) % HO, co = (id / (HO * HO)) % 4, b = id / (HO * HO * 4);
    float acc = bias[co];
    for (int ci = 0; ci < 3; ++ci) {
        const float* xp = x + ((size_t)b * 3 + ci) * 65536;
        const float* wp = w + (co * 3 + ci) * 9;
        #pragma unroll
        for (int ky = 0; ky < 3; ++ky) {
            int iy = oy * S - 1 + ky;
            if (iy < 0 || iy >= 256) continue;
            #pragma unroll
            for (int kx = 0; kx < 3; ++kx) {
                int ix = ox * S - 1 + kx;
                if (ix < 0 || ix >= 256) continue;
                acc = fmaf(xp[iy * 256 + ix], wp[ky * 3 + kx], acc);
            }
        }
    }
    out[id] = acc;
}

// ---------------- entropy (KDE), gray fused ----------------
__global__ __launch_bounds__(256) void entropy_kernel(const float* __restrict__ x,
                                                      float* __restrict__ ent) {
    __shared__ float s_patch[256];
    __shared__ float s_red[4];
    int blk = blockIdx.x;
    int b = blk >> 8, rem = blk & 255;
    int py = rem >> 4, px = rem & 15;
    int tid = threadIdx.x;
    int pr = tid >> 4, pc = tid & 15;
    const float* xb = x + (size_t)b * 3 * 65536;
    int p = (py * 16 + pr) * 256 + (px * 16 + pc);
    s_patch[tid] = 0.299f * xb[p] + 0.587f * xb[65536 + p] + 0.114f * xb[2 * 65536 + p];
    __syncthreads();

    float bin = (float)tid * (1.0f / 255.0f);
    float s = 0.f;
    #pragma unroll 8
    for (int q = 0; q < 256; ++q) {
        float t = (s_patch[q] - bin) * 100.0f;
        s += expf(-0.5f * (t * t));
    }
    float pdf = s * (1.0f / 256.0f);

    float r = pdf;
    #pragma unroll
    for (int o = 32; o > 0; o >>= 1) r += __shfl_down(r, o, 64);
    if ((tid & 63) == 0) s_red[tid >> 6] = r;
    __syncthreads();
    float total = s_red[0] + s_red[1] + s_red[2] + s_red[3];
    __syncthreads();

    float p2 = pdf / total;
    p2 = fmaxf(p2, 1e-10f);
    float e = -p2 * log2f(p2);
    #pragma unroll
    for (int o = 32; o > 0; o >>= 1) e += __shfl_down(e, o, 64);
    if ((tid & 63) == 0) s_red[tid >> 6] = e;
    __syncthreads();
    if (tid == 0) ent[blk] = s_red[0] + s_red[1] + s_red[2] + s_red[3];
}

// ---------------- median of 2048 values (bitonic sort) ----------------
__global__ __launch_bounds__(1024) void median_kernel(const float* __restrict__ ent,
                                                      float* __restrict__ thr) {
    __shared__ float s[2048];
    int tid = threadIdx.x;
    s[tid] = ent[tid];
    s[tid + 1024] = ent[tid + 1024];
    __syncthreads();
    for (int k = 2; k <= 2048; k <<= 1) {
        for (int j = k >> 1; j > 0; j >>= 1) {
            int t = tid;
            #pragma unroll 1
            for (int rep = 0; rep < 2; ++rep, t += 1024) {
                int ixj = t ^ j;
                if (ixj > t) {
                    float a = s[t], bb = s[ixj];
                    bool up = ((t & k) == 0);
                    bool sw = up ? (a > bb) : (a < bb);
                    if (sw) { s[t] = bb; s[ixj] = a; }
                }
            }
            __syncthreads();
        }
    }
    if (tid == 0) *thr = 0.5f * (s[1023] + s[1024]);
}

__global__ void grain_kernel(const float* __restrict__ ent, const float* __restrict__ thr,
                             float* __restrict__ grain) {
    int id = blockIdx.x * 256 + threadIdx.x;
    if (id >= 2048) return;
    grain[id] = (ent[id] > *thr) ? 1.0f : 0.0f;
}

__global__ void route_kernel(const float* __restrict__ latf, const float* __restrict__ latc,
                             const float* __restrict__ grain, float* __restrict__ routed) {
    int id = blockIdx.x * 256 + threadIdx.x;
    if (id >= B * 4 * 32 * 32) return;
    int xx = id & 31, yy = (id >> 5) & 31, c = (id >> 10) & 3, b = id >> 12;
    float g = grain[b * 256 + (yy >> 1) * 16 + (xx >> 1)];
    float cu = latc[((b * 4 + c) * 16 + (yy >> 1)) * 16 + (xx >> 1)];
    routed[id] = g * latf[id] + (1.0f - g) * cu;
}

// ---------------- fp32 conv 3x3 (used for Wi and final co) ----------------
template<int CIN, int COUT, int H, int W, int CI_BLK, int CO_BLK, int ACT>
__global__ __launch_bounds__(256) void conv3x3(const float* __restrict__ in,
                                               const float* __restrict__ wgt,
                                               const float* __restrict__ bias,
                                               float* __restrict__ out) {
    constexpr int TW = W / 16;
    __shared__ float s_in[CI_BLK][18][18];
    __shared__ float s_w[CI_BLK][9][CO_BLK];
    const int tid = threadIdx.x;
    const int lx = tid & 15, ly = tid >> 4;
    const int co0 = blockIdx.x * CO_BLK;
    const int tile = blockIdx.y;
    const int tx0 = (tile % TW) * 16, ty0 = (tile / TW) * 16;
    const int ox = tx0 + lx, oy = ty0 + ly;

    float acc[CO_BLK];
    #pragma unroll
    for (int i = 0; i < CO_BLK; ++i) acc[i] = bias[co0 + i];

    for (int ci0 = 0; ci0 < CIN; ci0 += CI_BLK) {
        for (int idx = tid; idx < CI_BLK * 324; idx += 256) {
            int ci = idx / 324, rm = idx % 324;
            int r = rm / 18, c = rm % 18;
            int iy = ty0 - 1 + r, ix = tx0 - 1 + c;
            float v = 0.f;
            if (iy >= 0 && iy < H && ix >= 0 && ix < W)
                v = in[((size_t)(ci0 + ci) * H + iy) * W + ix];
            s_in[ci][r][c] = v;
        }
        for (int idx = tid; idx < CI_BLK * 9 * CO_BLK; idx += 256) {
            int ci = idx / (9 * CO_BLK), rm = idx % (9 * CO_BLK);
            int k = rm / CO_BLK, co = rm % CO_BLK;
            s_w[ci][k][co] = wgt[((size_t)(co0 + co) * CIN + ci0 + ci) * 9 + k];
        }
        __syncthreads();
        #pragma unroll
        for (int ci = 0; ci < CI_BLK; ++ci) {
            float v[9];
            #pragma unroll
            for (int ky = 0; ky < 3; ++ky)
                #pragma unroll
                for (int kx = 0; kx < 3; ++kx)
                    v[ky * 3 + kx] = s_in[ci][ly + ky][lx + kx];
            if constexpr ((CO_BLK & 3) == 0) {
                #pragma unroll
                for (int k = 0; k < 9; ++k) {
                    #pragma unroll
                    for (int c4 = 0; c4 < CO_BLK / 4; ++c4) {
                        const float4 w4 = *reinterpret_cast<const float4*>(&s_w[ci][k][c4 * 4]);
                        acc[c4 * 4 + 0] = fmaf(v[k], w4.x, acc[c4 * 4 + 0]);
                        acc[c4 * 4 + 1] = fmaf(v[k], w4.y, acc[c4 * 4 + 1]);
                        acc[c4 * 4 + 2] = fmaf(v[k], w4.z, acc[c4 * 4 + 2]);
                        acc[c4 * 4 + 3] = fmaf(v[k], w4.w, acc[c4 * 4 + 3]);
                    }
                }
            } else {
                #pragma unroll
                for (int k = 0; k < 9; ++k)
                    #pragma unroll
                    for (int co = 0; co < CO_BLK; ++co)
                        acc[co] = fmaf(v[k], s_w[ci][k][co], acc[co]);
            }
        }
        __syncthreads();
    }
    #pragma unroll
    for (int co = 0; co < CO_BLK; ++co) {
        float v = acc[co];
        if (ACT == 1) v = fmaxf(v, 0.f);
        if (ACT == 2) v = tanhf(v);
        out[((size_t)(co0 + co) * H + oy) * W + ox] = v;
    }
}

// ---------------- weight pre-split: fp32 [co][ci][3][3] -> bf16 hi/lo -------
// dst layout: [cob][ch][2(hi,lo)][tap9][co64][ci16]
__global__ void wsplit_kernel(const float* __restrict__ w, unsigned short* __restrict__ dst,
                              int CIN, int COUT) {
    int idx = blockIdx.x * 256 + threadIdx.x;
    int total = COUT * CIN * 9;
    if (idx >= total) return;
    int t = idx % 9;
    int ci = (idx / 9) % CIN;
    int co = idx / (9 * CIN);
    float x = w[idx];
    unsigned short h = f2bf(x);
    unsigned short l = f2bf(x - bf2f(h));
    int CH = CIN >> 4;
    int cob = co >> 6, col = co & 63, ch = ci >> 4, cil = ci & 15;
    size_t base = ((size_t)(cob * CH + ch) * 2) * 9216 + (size_t)t * 1024 + col * 16 + cil;
    dst[base] = h;
    dst[base + 9216] = l;
}

// ---------------- MFMA conv3x3 (split-bf16, 3-term) ------------------------
// In: bf16 hi/lo planes [y][x][cin]; W: pre-split slot; Out: fp32 planar +ReLU.
// Block 256 thr = 4 waves; wave w: rows [w*P, w*P+P), 32 px, 64 couts (2 grp).
// D = A(W: m=cout) x B(X: n=px), K = 16 cin per MFMA, 9 taps unrolled.
template<int CIN, int COUT, int H, int W, int R>
__global__ __launch_bounds__(256) void convM(const unsigned short* __restrict__ xh_base,
                                             const unsigned short* __restrict__ wsp,
                                             const float* __restrict__ bias,
                                             float* __restrict__ out) {
    constexpr int P = R / 4;
    constexpr int CH = CIN / 16;
    __shared__ __align__(16) unsigned short sX[2][R + 2][34][16];
    __shared__ __align__(16) unsigned short sW[2][9][64][16];
    const unsigned short* xl_base = xh_base + (size_t)H * W * CIN;
    const int tid = threadIdx.x;
    const int lane = tid & 63, wv = tid >> 6;
    const int n = lane & 31, kh = lane >> 5;
    const int x0 = blockIdx.x * 32;
    const int y0 = blockIdx.y * R;
    const int cob = blockIdx.z;
    const unsigned short* wchunks = wsp + (size_t)cob * CH * 18432;

    f32x16 acc[P][2];
    #pragma unroll
    for (int p = 0; p < P; ++p) {
        acc[p][0] = (f32x16)0.0f;
        acc[p][1] = (f32x16)0.0f;
    }

    for (int ch = 0; ch < CH; ++ch) {
        __syncthreads();
        const int ci0 = ch * 16;
        // stage X chunk: rows y0-1..y0+R, cols x0-1..x0+32, 16 cin (u64 = 4 cin)
        for (int i = tid; i < (R + 2) * 34 * 4; i += 256) {
            int q = i & 3, pos = i >> 2;
            int rr = pos / 34, xc = pos - rr * 34;
            int gy = y0 - 1 + rr, gx = x0 - 1 + xc;
            uint2 vh = make_uint2(0u, 0u), vl = make_uint2(0u, 0u);
            if (gy >= 0 && gy < H && gx >= 0 && gx < W) {
                size_t g = ((size_t)gy * W + gx) * CIN + ci0 + q * 4;
                vh = *(const uint2*)&xh_base[g];
                vl = *(const uint2*)&xl_base[g];
            }
            *(uint2*)&sX[0][rr][xc][q * 4] = vh;
            *(uint2*)&sX[1][rr][xc][q * 4] = vl;
        }
        // stage W chunk: one contiguous 36864 B copy
        {
            const char* wsrc = (const char*)(wchunks + (size_t)ch * 18432);
            char* wdst = (char*)&sW[0][0][0][0];
            for (int i = tid; i < 2304; i += 256) {
                uint4 v = *(const uint4*)(wsrc + (size_t)i * 16);
                *(uint4*)(wdst + (size_t)i * 16) = v;
            }
        }
        __syncthreads();
        #pragma unroll
        for (int t = 0; t < 9; ++t) {
            const int ky = t / 3, kx = t % 3;
            short8 wh0 = *(const short8*)&sW[0][t][n][kh * 8];
            short8 wh1 = *(const short8*)&sW[0][t][32 + n][kh * 8];
            short8 wl0 = *(const short8*)&sW[1][t][n][kh * 8];
            short8 wl1 = *(const short8*)&sW[1][t][32 + n][kh * 8];
            #pragma unroll
            for (int p = 0; p < P; ++p) {
                const int r = wv * P + p + ky;
                short8 xh = *(const short8*)&sX[0][r][n + kx][kh * 8];
                short8 xl = *(const short8*)&sX[1][r][n + kx][kh * 8];
                acc[p][0] = __builtin_amdgcn_mfma_f32_32x32x16_bf16(wh0, xh, acc[p][0], 0, 0, 0);
                acc[p][1] = __builtin_amdgcn_mfma_f32_32x32x16_bf16(wh1, xh, acc[p][1], 0, 0, 0);
                acc[p][0] = __builtin_amdgcn_mfma_f32_32x32x16_bf16(wh0, xl, acc[p][0], 0, 0, 0);
                acc[p][1] = __builtin_amdgcn_mfma_f32_32x32x16_bf16(wh1, xl, acc[p][1], 0, 0, 0);
                acc[p][0] = __builtin_amdgcn_mfma_f32_32x32x16_bf16(wl0, xh, acc[p][0], 0, 0, 0);
                acc[p][1] = __builtin_amdgcn_mfma_f32_32x32x16_bf16(wl1, xh, acc[p][1], 0, 0, 0);
            }
        }
    }
    // epilogue: bias + ReLU, coalesced 128B stores per (p,cg,reg)
    #pragma unroll
    for (int p = 0; p < P; ++p) {
        const int y = y0 + wv * P + p;
        #pragma unroll
        for (int cg = 0; cg < 2; ++cg) {
            #pragma unroll
            for (int reg = 0; reg < 16; ++reg) {
                int col = (reg & 3) + 8 * (reg >> 2) + 4 * kh;   // m74-verified C/D row
                int co = cob * 64 + cg * 32 + col;
                float v = acc[p][cg][reg] + bias[co];
                out[((size_t)co * H + y) * W + (x0 + n)] = fmaxf(v, 0.f);
            }
        }
    }
}

// ---------------- deconv (parity-split quad) -> bf16 hi/lo planes + ReLU ----
template<int CIN, int COUT, int HIN, int WIN, int CI_BLK, int CO_BLK>
__global__ __launch_bounds__(256) void deconvP(const float* __restrict__ in,
                                               const float* __restrict__ wgt,
                                               const float* __restrict__ bias,
                                               unsigned short* __restrict__ outp) {
    constexpr int HO = 2 * HIN, WO = 2 * WIN;
    constexpr int QTW = WIN / 16;
    __shared__ float s_in[CI_BLK][17][18];
    __shared__ float s_w[CI_BLK][9][CO_BLK];
    unsigned short* outl = outp + (size_t)HO * WO * COUT;
    const int tid = threadIdx.x;
    const int qx = tid & 15, qy = tid >> 4;
    const int co0 = blockIdx.x * CO_BLK;
    const int tile = blockIdx.y;
    const int c0 = (tile % QTW) * 16, r0 = (tile / QTW) * 16;
    const int r = r0 + qy, c = c0 + qx;

    float acc[4][CO_BLK];                          // 0=ee 1=eo 2=oe 3=oo
    #pragma unroll
    for (int p = 0; p < 4; ++p)
        #pragma unroll
        for (int i = 0; i < CO_BLK; ++i) acc[p][i] = 0.f;

    for (int ci0 = 0; ci0 < CIN; ci0 += CI_BLK) {
        for (int idx = tid; idx < CI_BLK * 17 * 18; idx += 256) {
            int ci = idx / (17 * 18), rm = idx % (17 * 18);
            int rr = rm / 18, cc = rm % 18;
            int iy = r0 + rr, ix = c0 + cc;
            float v = 0.f;
            if (cc < 17 && iy < HIN && ix < WIN)
                v = in[((size_t)(ci0 + ci) * HIN + iy) * WIN + ix];
            s_in[ci][rr][cc] = v;
        }
        for (int idx = tid; idx < CI_BLK * 9 * CO_BLK; idx += 256) {
            int ci = idx / (9 * CO_BLK), rm = idx % (9 * CO_BLK);
            int k = rm / CO_BLK, co = rm % CO_BLK;
            s_w[ci][k][co] = wgt[((size_t)(ci0 + ci) * COUT + co0 + co) * 9 + k];
        }
        __syncthreads();
        #pragma unroll
        for (int ci = 0; ci < CI_BLK; ++ci) {
            const float iv[4] = { s_in[ci][qy][qx],     s_in[ci][qy][qx + 1],
                                  s_in[ci][qy + 1][qx], s_in[ci][qy + 1][qx + 1] };
            #pragma unroll
            for (int k = 0; k < 9; ++k) {
                constexpr int SRC[9] = {3, 2, 2, 1, 0, 0, 1, 0, 0};
                constexpr int DST[9] = {3, 2, 3, 1, 0, 1, 3, 2, 3};
                #pragma unroll
                for (int c4 = 0; c4 < CO_BLK / 4; ++c4) {
                    const float4 w4 = *reinterpret_cast<const float4*>(&s_w[ci][k][c4 * 4]);
                    acc[DST[k]][c4 * 4 + 0] = fmaf(iv[SRC[k]], w4.x, acc[DST[k]][c4 * 4 + 0]);
                    acc[DST[k]][c4 * 4 + 1] = fmaf(iv[SRC[k]], w4.y, acc[DST[k]][c4 * 4 + 1]);
                    acc[DST[k]][c4 * 4 + 2] = fmaf(iv[SRC[k]], w4.z, acc[DST[k]][c4 * 4 + 2]);
                    acc[DST[k]][c4 * 4 + 3] = fmaf(iv[SRC[k]], w4.w, acc[DST[k]][c4 * 4 + 3]);
                }
            }
        }
        __syncthreads();
    }
    const int oy0 = 2 * r, ox0 = 2 * c;
    float bv[CO_BLK];
    #pragma unroll
    for (int co = 0; co < CO_BLK; ++co) bv[co] = bias[co0 + co];
    #pragma unroll
    for (int py = 0; py < 2; ++py) {
        #pragma unroll
        for (int px = 0; px < 2; ++px) {
            const int p = py * 2 + px;
            size_t base = ((size_t)(oy0 + py) * WO + (ox0 + px)) * COUT + co0;
            if constexpr (CO_BLK == 8) {
                short8 vh, vl;
                #pragma unroll
                for (int co = 0; co < 8; ++co) {
                    float v = fmaxf(acc[p][co] + bv[co], 0.f);
                    unsigned short h = f2bf(v);
                    vh[co] = (short)h;
                    vl[co] = (short)f2bf(v - bf2f(h));
                }
                *(short8*)&outp[base] = vh;
                *(short8*)&outl[base] = vl;
            } else {
                short4v vh, vl;
                #pragma unroll
                for (int co = 0; co < CO_BLK; ++co) {
                    float v = fmaxf(acc[p][co] + bv[co], 0.f);
                    unsigned short h = f2bf(v);
                    vh[co] = (short)h;
                    vl[co] = (short)f2bf(v - bf2f(h));
                }
                *(short4v*)&outp[base] = vh;
                *(short4v*)&outl[base] = vl;
            }
        }
    }
}

// ---------------------------------------------------------------------------
extern "C" void kernel_launch(void* const* d_in, const int* in_sizes, int n_in,
                              void* d_out, int out_size, void* d_ws, size_t ws_size,
                              hipStream_t stream) {
    const float* x   = (const float*)d_in[0];
    const float* We0 = (const float*)d_in[1];  const float* be0 = (const float*)d_in[2];
    const float* We1 = (const float*)d_in[3];  const float* be1 = (const float*)d_in[4];
    const float* Wi  = (const float*)d_in[5];  const float* bi  = (const float*)d_in[6];
    const float* Wd1 = (const float*)d_in[7];  const float* bd1 = (const float*)d_in[8];
    const float* Wc1 = (const float*)d_in[9];  const float* bc1 = (const float*)d_in[10];
    const float* Wd2 = (const float*)d_in[11]; const float* bd2 = (const float*)d_in[12];
    const float* Wc2 = (const float*)d_in[13]; const float* bc2 = (const float*)d_in[14];
    const float* Wd3 = (const float*)d_in[15]; const float* bd3 = (const float*)d_in[16];
    const float* Wc3 = (const float*)d_in[17]; const float* bc3 = (const float*)d_in[18];
    const float* Wo  = (const float*)d_in[19]; const float* bo  = (const float*)d_in[20];

    float* out    = (float*)d_out;
    float* rec    = out;               // [8,3,256,256]
    float* routed = out + 1572864;     // [8,4,32,32]
    float* grain  = out + 1605632;     // [8,16,16]
    float* ent    = out + 1607680;     // [8,16,16]

    // latent scratch in rec's region: dead before first rec write.
    float* latf = out;                 // 32768 floats
    float* latc = out + 32768;         // 8192 floats
    float* thr  = out + 40960;         // 1 float
    // Wc3 split slot: last 147456 floats of rec == inside rec[7] slice.
    // Written before c3(b), overwritten only by co(7) at the very end.
    unsigned short* slot3 = (unsigned short*)(out + 1425408);

    // workspace: 64 MB — U (fp32 ping) | V (bf16 hi/lo planes)
    char* ws8 = (char*)d_ws;
    float*          U     = (float*)ws8;
    unsigned short* Vp    = (unsigned short*)(ws8 + (size_t)32 * 1024 * 1024);
    unsigned short* wspC1 = (unsigned short*)(ws8 + (size_t)16 * 1024 * 1024);       // 2.36MB, dead zone of U
    unsigned short* wspC2 = (unsigned short*)(ws8 + (size_t)(32 + 24) * 1024 * 1024); // 0.59MB, dead zone of V

    // --- entropy / routing path ---
    enc_conv_kernel<<<128, 256, 0, stream>>>(x, We0, be0, latf, 8, 32);
    enc_conv_kernel<<<32, 256, 0, stream>>>(x, We1, be1, latc, 16, 16);
    entropy_kernel<<<2048, 256, 0, stream>>>(x, ent);
    median_kernel<<<1, 1024, 0, stream>>>(ent, thr);
    grain_kernel<<<8, 256, 0, stream>>>(ent, thr, grain);
    route_kernel<<<128, 256, 0, stream>>>(latf, latc, grain, routed);

    // --- decoder, per batch ---
    for (int b = 0; b < B; ++b) {
        const float* rb = routed + (size_t)b * 4 * 32 * 32;
        float* recb = rec + (size_t)b * 3 * 65536;
        // Wi: routed -> h (fp32, U[0..1MB])
        conv3x3<4, 256, 32, 32, 4, 16, 0><<<dim3(16, 4, 1), 256, 0, stream>>>(rb, Wi, bi, U);
        // d1: h -> V planes (bf16 hi/lo, 4MB)
        deconvP<256, 256, 32, 32, 8, 4><<<dim3(64, 4, 1), 256, 0, stream>>>(U, Wd1, bd1, Vp);
        // c1: V + Wc1split -> U fp32 (4MB)
        wsplit_kernel<<<2304, 256, 0, stream>>>(Wc1, wspC1, 256, 256);
        convM<256, 256, 64, 64, 4><<<dim3(2, 16, 4), 256, 0, stream>>>(Vp, wspC1, bc1, U);
        // d2: U -> V planes (8MB)
        deconvP<256, 128, 64, 64, 8, 8><<<dim3(16, 16, 1), 256, 0, stream>>>(U, Wd2, bd2, Vp);
        // c2: V + Wc2split -> U fp32 (8MB)
        wsplit_kernel<<<576, 256, 0, stream>>>(Wc2, wspC2, 128, 128);
        convM<128, 128, 128, 128, 4><<<dim3(4, 32, 2), 256, 0, stream>>>(Vp, wspC2, bc2, U);
        // d3: U -> V planes (32MB)
        deconvP<128, 128, 128, 128, 8, 8><<<dim3(16, 64, 1), 256, 0, stream>>>(U, Wd3, bd3, Vp);
        // c3: V + Wc3split(rec slot) -> U fp32 (32MB)
        wsplit_kernel<<<576, 256, 0, stream>>>(Wc3, slot3, 128, 128);
        convM<128, 128, 256, 256, 8><<<dim3(8, 32, 2), 256, 0, stream>>>(Vp, slot3, bc3, U);
        // co: U -> rec (tanh)
        conv3x3<128, 3, 256, 256, 8, 3, 2><<<dim3(1, 256, 1), 256, 0, stream>>>(U, Wo, bo, recb);
    }
}

// Round 6
// 3631.008 us; speedup vs baseline: 5.5699x; 1.8224x over previous
//
#include <hip/hip_runtime.h>
#include <hip/hip_bf16.h>
#include <cstdint>
#include <cstddef>

// ---------------------------------------------------------------------------
// DVAE forward v5.1: whole decoder (convs AND deconvs) on MFMA split-bf16.
// v5 bug fixed: sW staging copies used HALF the uint4 count (lo-split weights
// never staged -> LDS garbage -> NaN). Copy counts now derived from sizeof.
// Activations between decoder stages: bf16 hi/lo planes, channel-blocked
//   A-format: elem(c,y,x) at ((c>>4)*H*W + y*W + x)*16 + (c&15); lo plane at
//   +H*W*C elements.
// LDS layouts use 16B cells ([hl][kh][...][8]) so wave reads are at 16B
//   stride -> conflict-free.
// deconv = parity-split: 4 output-position accumulators, 9 taps, SRC/DST
//   table verified in rounds 2-4.
// Weight pre-split slots (per batch, dead-zone audited):
//   wspD1 U+16M(2.36M) wspD2 U+20M(1.18M) wspD3 U+22M(0.59M)
//   wspC1 V+16M(2.36M) wspC2 V+20M(0.59M) wspC3 rec[7] tail.
// ---------------------------------------------------------------------------

#define B 8

typedef __attribute__((ext_vector_type(8)))  short  short8;
typedef __attribute__((ext_vector_type(4)))  short  short4v;
typedef __attribute__((ext_vector_type(16))) float  f32x16;

__device__ inline unsigned short f2bf(float x) {          // RNE f32->bf16
    uint32_t u = __float_as_uint(x);
    uint32_t r = (u + 0x7FFFu + ((u >> 16) & 1u)) >> 16;
    return (unsigned short)r;
}
__device__ inline float bf2f(unsigned short h) {
    return __uint_as_float(((uint32_t)h) << 16);
}

// ---------------- encoder strided conv (Cin=3, Cout=4, k=3, pad=1) ----------
__global__ void enc_conv_kernel(const float* __restrict__ x, const float* __restrict__ w,
                                const float* __restrict__ bias, float* __restrict__ out,
                                int S, int HO) {
    int id = blockIdx.x * 256 + threadIdx.x;
    int total = B * 4 * HO * HO;
    if (id >= total) return;
    int ox = id % HO, oy = (id / HO) % HO, co = (id / (HO * HO)) % 4, b = id / (HO * HO * 4);
    float acc = bias[co];
    for (int ci = 0; ci < 3; ++ci) {
        const float* xp = x + ((size_t)b * 3 + ci) * 65536;
        const float* wp = w + (co * 3 + ci) * 9;
        #pragma unroll
        for (int ky = 0; ky < 3; ++ky) {
            int iy = oy * S - 1 + ky;
            if (iy < 0 || iy >= 256) continue;
            #pragma unroll
            for (int kx = 0; kx < 3; ++kx) {
                int ix = ox * S - 1 + kx;
                if (ix < 0 || ix >= 256) continue;
                acc = fmaf(xp[iy * 256 + ix], wp[ky * 3 + kx], acc);
            }
        }
    }
    out[id] = acc;
}

// ---------------- entropy (KDE), gray fused ----------------
__global__ __launch_bounds__(256) void entropy_kernel(const float* __restrict__ x,
                                                      float* __restrict__ ent) {
    __shared__ float s_patch[256];
    __shared__ float s_red[4];
    int blk = blockIdx.x;
    int b = blk >> 8, rem = blk & 255;
    int py = rem >> 4, px = rem & 15;
    int tid = threadIdx.x;
    int pr = tid >> 4, pc = tid & 15;
    const float* xb = x + (size_t)b * 3 * 65536;
    int p = (py * 16 + pr) * 256 + (px * 16 + pc);
    s_patch[tid] = 0.299f * xb[p] + 0.587f * xb[65536 + p] + 0.114f * xb[2 * 65536 + p];
    __syncthreads();

    float bin = (float)tid * (1.0f / 255.0f);
    float s = 0.f;
    #pragma unroll 8
    for (int q = 0; q < 256; ++q) {
        float t = (s_patch[q] - bin) * 100.0f;
        s += expf(-0.5f * (t * t));
    }
    float pdf = s * (1.0f / 256.0f);

    float r = pdf;
    #pragma unroll
    for (int o = 32; o > 0; o >>= 1) r += __shfl_down(r, o, 64);
    if ((tid & 63) == 0) s_red[tid >> 6] = r;
    __syncthreads();
    float total = s_red[0] + s_red[1] + s_red[2] + s_red[3];
    __syncthreads();

    float p2 = pdf / total;
    p2 = fmaxf(p2, 1e-10f);
    float e = -p2 * log2f(p2);
    #pragma unroll
    for (int o = 32; o > 0; o >>= 1) e += __shfl_down(e, o, 64);
    if ((tid & 63) == 0) s_red[tid >> 6] = e;
    __syncthreads();
    if (tid == 0) ent[blk] = s_red[0] + s_red[1] + s_red[2] + s_red[3];
}

// ---------------- median of 2048 values (bitonic sort) ----------------
__global__ __launch_bounds__(1024) void median_kernel(const float* __restrict__ ent,
                                                      float* __restrict__ thr) {
    __shared__ float s[2048];
    int tid = threadIdx.x;
    s[tid] = ent[tid];
    s[tid + 1024] = ent[tid + 1024];
    __syncthreads();
    for (int k = 2; k <= 2048; k <<= 1) {
        for (int j = k >> 1; j > 0; j >>= 1) {
            int t = tid;
            #pragma unroll 1
            for (int rep = 0; rep < 2; ++rep, t += 1024) {
                int ixj = t ^ j;
                if (ixj > t) {
                    float a = s[t], bb = s[ixj];
                    bool up = ((t & k) == 0);
                    bool sw = up ? (a > bb) : (a < bb);
                    if (sw) { s[t] = bb; s[ixj] = a; }
                }
            }
            __syncthreads();
        }
    }
    if (tid == 0) *thr = 0.5f * (s[1023] + s[1024]);
}

__global__ void grain_kernel(const float* __restrict__ ent, const float* __restrict__ thr,
                             float* __restrict__ grain) {
    int id = blockIdx.x * 256 + threadIdx.x;
    if (id >= 2048) return;
    grain[id] = (ent[id] > *thr) ? 1.0f : 0.0f;
}

__global__ void route_kernel(const float* __restrict__ latf, const float* __restrict__ latc,
                             const float* __restrict__ grain, float* __restrict__ routed) {
    int id = blockIdx.x * 256 + threadIdx.x;
    if (id >= B * 4 * 32 * 32) return;
    int xx = id & 31, yy = (id >> 5) & 31, c = (id >> 10) & 3, b = id >> 12;
    float g = grain[b * 256 + (yy >> 1) * 16 + (xx >> 1)];
    float cu = latc[((b * 4 + c) * 16 + (yy >> 1)) * 16 + (xx >> 1)];
    routed[id] = g * latf[id] + (1.0f - g) * cu;
}

// ---------------- fp32 conv3x3 (Wi -> A-format; co -> planar/tanh) ----------
// OUTM: 0 = fp32 planar, 1 = bf16 hi/lo A-format.
template<int CIN, int COUT, int H, int W, int CI_BLK, int CO_BLK, int ACT, int OUTM>
__global__ __launch_bounds__(256) void conv3x3(const float* __restrict__ in,
                                               const float* __restrict__ wgt,
                                               const float* __restrict__ bias,
                                               void* __restrict__ outv) {
    constexpr int TW = W / 16;
    __shared__ float s_in[CI_BLK][18][18];
    __shared__ float s_w[CI_BLK][9][CO_BLK];
    const int tid = threadIdx.x;
    const int lx = tid & 15, ly = tid >> 4;
    const int co0 = blockIdx.x * CO_BLK;
    const int tile = blockIdx.y;
    const int tx0 = (tile % TW) * 16, ty0 = (tile / TW) * 16;
    const int ox = tx0 + lx, oy = ty0 + ly;

    float acc[CO_BLK];
    #pragma unroll
    for (int i = 0; i < CO_BLK; ++i) acc[i] = bias[co0 + i];

    for (int ci0 = 0; ci0 < CIN; ci0 += CI_BLK) {
        for (int idx = tid; idx < CI_BLK * 324; idx += 256) {
            int ci = idx / 324, rm = idx % 324;
            int r = rm / 18, c = rm % 18;
            int iy = ty0 - 1 + r, ix = tx0 - 1 + c;
            float v = 0.f;
            if (iy >= 0 && iy < H && ix >= 0 && ix < W)
                v = in[((size_t)(ci0 + ci) * H + iy) * W + ix];
            s_in[ci][r][c] = v;
        }
        for (int idx = tid; idx < CI_BLK * 9 * CO_BLK; idx += 256) {
            int ci = idx / (9 * CO_BLK), rm = idx % (9 * CO_BLK);
            int k = rm / CO_BLK, co = rm % CO_BLK;
            s_w[ci][k][co] = wgt[((size_t)(co0 + co) * CIN + ci0 + ci) * 9 + k];
        }
        __syncthreads();
        #pragma unroll
        for (int ci = 0; ci < CI_BLK; ++ci) {
            float v[9];
            #pragma unroll
            for (int ky = 0; ky < 3; ++ky)
                #pragma unroll
                for (int kx = 0; kx < 3; ++kx)
                    v[ky * 3 + kx] = s_in[ci][ly + ky][lx + kx];
            if constexpr ((CO_BLK & 3) == 0) {
                #pragma unroll
                for (int k = 0; k < 9; ++k) {
                    #pragma unroll
                    for (int c4 = 0; c4 < CO_BLK / 4; ++c4) {
                        const float4 w4 = *reinterpret_cast<const float4*>(&s_w[ci][k][c4 * 4]);
                        acc[c4 * 4 + 0] = fmaf(v[k], w4.x, acc[c4 * 4 + 0]);
                        acc[c4 * 4 + 1] = fmaf(v[k], w4.y, acc[c4 * 4 + 1]);
                        acc[c4 * 4 + 2] = fmaf(v[k], w4.z, acc[c4 * 4 + 2]);
                        acc[c4 * 4 + 3] = fmaf(v[k], w4.w, acc[c4 * 4 + 3]);
                    }
                }
            } else {
                #pragma unroll
                for (int k = 0; k < 9; ++k)
                    #pragma unroll
                    for (int co = 0; co < CO_BLK; ++co)
                        acc[co] = fmaf(v[k], s_w[ci][k][co], acc[co]);
            }
        }
        __syncthreads();
    }
    #pragma unroll
    for (int co = 0; co < CO_BLK; ++co) {
        float v = acc[co];
        if (ACT == 1) v = fmaxf(v, 0.f);
        if (ACT == 2) v = tanhf(v);
        if constexpr (OUTM == 0) {
            ((float*)outv)[((size_t)(co0 + co) * H + oy) * W + ox] = v;
        } else {
            unsigned short* o = (unsigned short*)outv;
            int c = co0 + co;
            unsigned short h = f2bf(v);
            unsigned short l = f2bf(v - bf2f(h));
            size_t a = ((size_t)(c >> 4) * H * W + (size_t)oy * W + ox) * 16 + (c & 15);
            o[a] = h;
            o[a + (size_t)H * W * COUT] = l;
        }
    }
}

// ---------------- fused weight pre-split -----------------------------------
// conv slot:   [cob(64co)][ch][hl][kh][t][co64][ci8]   (18432 shorts / (cob,ch))
// deconv slot: [cob(32co)][ch][hl][kh][t][co32][ci8]   ( 9216 shorts / (cob,ch))
__device__ inline void wsplit_conv_one(const float* __restrict__ w, unsigned short* dst,
                                       int CIN, int idx) {
    int t = idx % 9;
    int ci = (idx / 9) % CIN;
    int co = idx / (9 * CIN);
    float x = w[idx];
    unsigned short h = f2bf(x);
    unsigned short l = f2bf(x - bf2f(h));
    int CH = CIN >> 4;
    int cob = co >> 6, col = co & 63;
    int ch = ci >> 4, kh = (ci >> 3) & 1, ci8 = ci & 7;
    size_t base = (size_t)(cob * CH + ch) * 18432 + (size_t)((kh * 9 + t) * 512) + col * 8 + ci8;
    dst[base] = h;
    dst[base + 9216] = l;       // hl=1 block
}
__device__ inline void wsplit_deconv_one(const float* __restrict__ w, unsigned short* dst,
                                         int CIN, int COUT, int idx) {
    int t = idx % 9;
    int co = (idx / 9) % COUT;
    int ci = idx / (9 * COUT);
    float x = w[idx];           // w[ci][co][t]
    unsigned short h = f2bf(x);
    unsigned short l = f2bf(x - bf2f(h));
    int CH = CIN >> 4;
    int cob = co >> 5, col = co & 31;
    int ch = ci >> 4, kh = (ci >> 3) & 1, ci8 = ci & 7;
    size_t base = (size_t)(cob * CH + ch) * 9216 + (size_t)((kh * 9 + t) * 256) + col * 8 + ci8;
    dst[base] = h;
    dst[base + 4608] = l;
}
__global__ void wsplit_all_kernel(const float* Wd1, const float* Wc1, const float* Wd2,
                                  const float* Wc2, const float* Wd3, const float* Wc3,
                                  unsigned short* pD1, unsigned short* pC1,
                                  unsigned short* pD2, unsigned short* pC2,
                                  unsigned short* pD3, unsigned short* pC3) {
    int gb = blockIdx.x, tid = threadIdx.x;
    if      (gb < 2304) wsplit_deconv_one(Wd1, pD1, 256, 256, gb * 256 + tid);
    else if (gb < 4608) wsplit_conv_one  (Wc1, pC1, 256, (gb - 2304) * 256 + tid);
    else if (gb < 5760) wsplit_deconv_one(Wd2, pD2, 256, 128, (gb - 4608) * 256 + tid);
    else if (gb < 6336) wsplit_conv_one  (Wc2, pC2, 128, (gb - 5760) * 256 + tid);
    else if (gb < 6912) wsplit_deconv_one(Wd3, pD3, 128, 128, (gb - 6336) * 256 + tid);
    else                wsplit_conv_one  (Wc3, pC3, 128, (gb - 6912) * 256 + tid);
}

// ---------------- MFMA conv3x3 (split-bf16 3-term) -------------------------
// In: A-format bf16 hi/lo. OUTM 0: fp32 planar + ReLU. OUTM 1: A-format +ReLU.
// Block = 4 waves; wave wv: P pixel-rows, 32 px, 64 couts.
template<int CIN, int COUT, int H, int W, int P, int OUTM>
__global__ __launch_bounds__(256) void convM(const unsigned short* __restrict__ xA,
                                             const unsigned short* __restrict__ wsp,
                                             const float* __restrict__ bias,
                                             void* __restrict__ outv) {
    constexpr int R = 4 * P;
    constexpr int CH = CIN / 16;
    constexpr size_t LIN = (size_t)H * W * CIN;
    constexpr size_t LOUT = (size_t)H * W * COUT;
    __shared__ __align__(16) unsigned short sX[2][2][R + 2][34][8];
    __shared__ __align__(16) unsigned short sW[2][2][9][64][8];
    const int tid = threadIdx.x;
    const int lane = tid & 63, wv = tid >> 6;
    const int n = lane & 31, kh = lane >> 5;
    const int x0 = blockIdx.x * 32;
    const int y0 = blockIdx.y * R;
    const int cob = blockIdx.z;
    const unsigned short* wblk = wsp + (size_t)cob * CH * 18432;

    f32x16 acc[P][2];
    #pragma unroll
    for (int p = 0; p < P; ++p) { acc[p][0] = (f32x16)0.0f; acc[p][1] = (f32x16)0.0f; }

    for (int ch = 0; ch < CH; ++ch) {
        __syncthreads();
        for (int i = tid; i < (R + 2) * 34 * 4; i += 256) {
            int sub = i & 3, hl = sub >> 1, khs = sub & 1;
            int cell = i >> 2, row = cell / 34, col = cell - row * 34;
            int gy = y0 - 1 + row, gx = x0 - 1 + col;
            uint4 v = make_uint4(0u, 0u, 0u, 0u);
            if (gy >= 0 && gy < H && gx >= 0 && gx < W)
                v = *(const uint4*)&xA[(size_t)hl * LIN +
                        ((size_t)(ch * H + gy) * W + gx) * 16 + khs * 8];
            *(uint4*)&sX[hl][khs][row][col][0] = v;
        }
        {
            // full sW copy: sizeof(sW)/16 uint4s (v5 bug: was half this)
            const uint4* src = (const uint4*)(wblk + (size_t)ch * 18432);
            uint4* dst = (uint4*)&sW[0][0][0][0][0];
            constexpr int NW = (int)(sizeof(sW) / 16);
            for (int i = tid; i < NW; i += 256) dst[i] = src[i];
        }
        __syncthreads();
        #pragma unroll
        for (int t = 0; t < 9; ++t) {
            const int ky = t / 3, kx = t % 3;
            short8 wh0 = *(const short8*)&sW[0][kh][t][n][0];
            short8 wh1 = *(const short8*)&sW[0][kh][t][32 + n][0];
            short8 wl0 = *(const short8*)&sW[1][kh][t][n][0];
            short8 wl1 = *(const short8*)&sW[1][kh][t][32 + n][0];
            #pragma unroll
            for (int p = 0; p < P; ++p) {
                const int row = wv * P + p + ky;
                short8 xh = *(const short8*)&sX[0][kh][row][n + kx][0];
                short8 xl = *(const short8*)&sX[1][kh][row][n + kx][0];
                acc[p][0] = __builtin_amdgcn_mfma_f32_32x32x16_bf16(wh0, xh, acc[p][0], 0, 0, 0);
                acc[p][1] = __builtin_amdgcn_mfma_f32_32x32x16_bf16(wh1, xh, acc[p][1], 0, 0, 0);
                acc[p][0] = __builtin_amdgcn_mfma_f32_32x32x16_bf16(wh0, xl, acc[p][0], 0, 0, 0);
                acc[p][1] = __builtin_amdgcn_mfma_f32_32x32x16_bf16(wh1, xl, acc[p][1], 0, 0, 0);
                acc[p][0] = __builtin_amdgcn_mfma_f32_32x32x16_bf16(wl0, xh, acc[p][0], 0, 0, 0);
                acc[p][1] = __builtin_amdgcn_mfma_f32_32x32x16_bf16(wl1, xh, acc[p][1], 0, 0, 0);
            }
        }
    }
    #pragma unroll
    for (int p = 0; p < P; ++p) {
        const int y = y0 + wv * P + p;
        #pragma unroll
        for (int cg = 0; cg < 2; ++cg) {
            if constexpr (OUTM == 0) {
                float* outF = (float*)outv;
                #pragma unroll
                for (int reg = 0; reg < 16; ++reg) {
                    int co = cob * 64 + cg * 32 + (reg & 3) + 8 * (reg >> 2) + 4 * kh;
                    float v = acc[p][cg][reg] + bias[co];
                    outF[((size_t)co * H + y) * W + (x0 + n)] = fmaxf(v, 0.f);
                }
            } else {
                unsigned short* outU = (unsigned short*)outv;
                #pragma unroll
                for (int grp = 0; grp < 4; ++grp) {
                    int co4 = cob * 64 + cg * 32 + grp * 8 + kh * 4;
                    short4v h4, l4;
                    #pragma unroll
                    for (int j = 0; j < 4; ++j) {
                        float v = fmaxf(acc[p][cg][grp * 4 + j] + bias[co4 + j], 0.f);
                        unsigned short h = f2bf(v);
                        h4[j] = (short)h;
                        l4[j] = (short)f2bf(v - bf2f(h));
                    }
                    size_t a = ((size_t)(co4 >> 4) * H * W + (size_t)y * W + (x0 + n)) * 16
                             + (co4 & 15);
                    *(short4v*)&outU[a] = h4;
                    *(short4v*)&outU[a + LOUT] = l4;
                }
            }
        }
    }
}

// ---------------- MFMA deconv (parity-split, split-bf16 3-term) -------------
// In/out: A-format bf16 hi/lo. Wave: 1 quad-row (32 quads) x 32 couts.
// Tap table (r2-verified): dy=SRC>>1, dx=SRC&1; DST in {0:ee,1:eo,2:oe,3:oo}.
template<int CIN, int COUT, int HIN, int WIN>
__global__ __launch_bounds__(256) void deconvM(const unsigned short* __restrict__ xA,
                                               const unsigned short* __restrict__ wsp,
                                               const float* __restrict__ bias,
                                               unsigned short* __restrict__ outA) {
    constexpr int HO = 2 * HIN, WO = 2 * WIN;
    constexpr int CH = CIN / 16;
    constexpr size_t LIN = (size_t)HIN * WIN * CIN;
    constexpr size_t LOUT = (size_t)HO * WO * COUT;
    __shared__ __align__(16) unsigned short sX[2][2][5][33][8];
    __shared__ __align__(16) unsigned short sW[2][2][9][32][8];
    const int tid = threadIdx.x;
    const int lane = tid & 63, wv = tid >> 6;
    const int n = lane & 31, kh = lane >> 5;
    const int x0 = blockIdx.x * 32;
    const int y0q = blockIdx.y * 4;
    const int cog = blockIdx.z;
    const unsigned short* wblk = wsp + (size_t)cog * CH * 9216;

    f32x16 acc[4];
    #pragma unroll
    for (int d = 0; d < 4; ++d) acc[d] = (f32x16)0.0f;

    for (int ch = 0; ch < CH; ++ch) {
        __syncthreads();
        for (int i = tid; i < 5 * 33 * 4; i += 256) {
            int sub = i & 3, hl = sub >> 1, khs = sub & 1;
            int cell = i >> 2, row = cell / 33, col = cell - row * 33;
            int gy = y0q + row, gx = x0 + col;
            uint4 v = make_uint4(0u, 0u, 0u, 0u);
            if (gy < HIN && gx < WIN)
                v = *(const uint4*)&xA[(size_t)hl * LIN +
                        ((size_t)(ch * HIN + gy) * WIN + gx) * 16 + khs * 8];
            *(uint4*)&sX[hl][khs][row][col][0] = v;
        }
        {
            // full sW copy: sizeof(sW)/16 uint4s (v5 bug: was half this)
            const uint4* src = (const uint4*)(wblk + (size_t)ch * 9216);
            uint4* dst = (uint4*)&sW[0][0][0][0][0];
            constexpr int NW = (int)(sizeof(sW) / 16);
            for (int i = tid; i < NW; i += 256) dst[i] = src[i];
        }
        __syncthreads();
        // preload the 2x2 input fragments (hi/lo)
        short8 xf[2][2][2];     // [hl][dy][dx]
        #pragma unroll
        for (int dy = 0; dy < 2; ++dy)
            #pragma unroll
            for (int dx = 0; dx < 2; ++dx) {
                xf[0][dy][dx] = *(const short8*)&sX[0][kh][wv + dy][n + dx][0];
                xf[1][dy][dx] = *(const short8*)&sX[1][kh][wv + dy][n + dx][0];
            }
        constexpr int SRC[9] = {3, 2, 2, 1, 0, 0, 1, 0, 0};
        constexpr int DST[9] = {3, 2, 3, 1, 0, 1, 3, 2, 3};
        #pragma unroll
        for (int t = 0; t < 9; ++t) {
            short8 wh = *(const short8*)&sW[0][kh][t][n][0];
            short8 wl = *(const short8*)&sW[1][kh][t][n][0];
            const int dy = SRC[t] >> 1, dx = SRC[t] & 1, d = DST[t];
            acc[d] = __builtin_amdgcn_mfma_f32_32x32x16_bf16(wh, xf[0][dy][dx], acc[d], 0, 0, 0);
            acc[d] = __builtin_amdgcn_mfma_f32_32x32x16_bf16(wh, xf[1][dy][dx], acc[d], 0, 0, 0);
            acc[d] = __builtin_amdgcn_mfma_f32_32x32x16_bf16(wl, xf[0][dy][dx], acc[d], 0, 0, 0);
        }
    }
    // epilogue: quad (y0q+wv, x0+n) -> out(2r+py, 2c+px), bf16 hi/lo A-format
    const int oyb = 2 * (y0q + wv), oxb = 2 * (x0 + n);
    #pragma unroll
    for (int pos = 0; pos < 4; ++pos) {
        const int oy = oyb + (pos >> 1), ox = oxb + (pos & 1);
        #pragma unroll
        for (int grp = 0; grp < 4; ++grp) {
            int co4 = cog * 32 + grp * 8 + kh * 4;
            short4v h4, l4;
            #pragma unroll
            for (int j = 0; j < 4; ++j) {
                float v = fmaxf(acc[pos][grp * 4 + j] + bias[co4 + j], 0.f);
                unsigned short h = f2bf(v);
                h4[j] = (short)h;
                l4[j] = (short)f2bf(v - bf2f(h));
            }
            size_t a = ((size_t)(co4 >> 4) * HO * WO + (size_t)oy * WO + ox) * 16 + (co4 & 15);
            *(short4v*)&outA[a] = h4;
            *(short4v*)&outA[a + LOUT] = l4;
        }
    }
}

// ---------------------------------------------------------------------------
extern "C" void kernel_launch(void* const* d_in, const int* in_sizes, int n_in,
                              void* d_out, int out_size, void* d_ws, size_t ws_size,
                              hipStream_t stream) {
    const float* x   = (const float*)d_in[0];
    const float* We0 = (const float*)d_in[1];  const float* be0 = (const float*)d_in[2];
    const float* We1 = (const float*)d_in[3];  const float* be1 = (const float*)d_in[4];
    const float* Wi  = (const float*)d_in[5];  const float* bi  = (const float*)d_in[6];
    const float* Wd1 = (const float*)d_in[7];  const float* bd1 = (const float*)d_in[8];
    const float* Wc1 = (const float*)d_in[9];  const float* bc1 = (const float*)d_in[10];
    const float* Wd2 = (const float*)d_in[11]; const float* bd2 = (const float*)d_in[12];
    const float* Wc2 = (const float*)d_in[13]; const float* bc2 = (const float*)d_in[14];
    const float* Wd3 = (const float*)d_in[15]; const float* bd3 = (const float*)d_in[16];
    const float* Wc3 = (const float*)d_in[17]; const float* bc3 = (const float*)d_in[18];
    const float* Wo  = (const float*)d_in[19]; const float* bo  = (const float*)d_in[20];

    float* out    = (float*)d_out;
    float* rec    = out;               // [8,3,256,256]
    float* routed = out + 1572864;     // [8,4,32,32]
    float* grain  = out + 1605632;     // [8,16,16]
    float* ent    = out + 1607680;     // [8,16,16]

    // latent scratch in rec region (dead before first rec write)
    float* latf = out;                 // 32768 floats
    float* latc = out + 32768;         // 8192 floats
    float* thr  = out + 40960;         // 1 float
    // Wc3 split slot: rec tail (147456 floats == 294912 shorts). Written per
    // batch before c3(b); co(7) overwrites it after the final c3 read.
    unsigned short* slotC3 = (unsigned short*)(out + 1425408);

    // workspace: 64 MB. U=ws[0,32M), V=ws[32M,64M).
    // Per-batch weight slots in dead zones (lifetimes audited in header).
    char* ws8 = (char*)d_ws;
    float*          U     = (float*)ws8;
    unsigned short* Uu    = (unsigned short*)ws8;
    unsigned short* Vp    = (unsigned short*)(ws8 + (size_t)32 * 1024 * 1024);
    unsigned short* wspD1 = (unsigned short*)(ws8 + (size_t)16 * 1024 * 1024);
    unsigned short* wspD2 = (unsigned short*)(ws8 + (size_t)20 * 1024 * 1024);
    unsigned short* wspD3 = (unsigned short*)(ws8 + (size_t)22 * 1024 * 1024);
    unsigned short* wspC1 = (unsigned short*)(ws8 + (size_t)48 * 1024 * 1024);
    unsigned short* wspC2 = (unsigned short*)(ws8 + (size_t)52 * 1024 * 1024);

    // --- entropy / routing path ---
    enc_conv_kernel<<<128, 256, 0, stream>>>(x, We0, be0, latf, 8, 32);
    enc_conv_kernel<<<32, 256, 0, stream>>>(x, We1, be1, latc, 16, 16);
    entropy_kernel<<<2048, 256, 0, stream>>>(x, ent);
    median_kernel<<<1, 1024, 0, stream>>>(ent, thr);
    grain_kernel<<<8, 256, 0, stream>>>(ent, thr, grain);
    route_kernel<<<128, 256, 0, stream>>>(latf, latc, grain, routed);

    // --- decoder, per batch ---
    for (int b = 0; b < B; ++b) {
        const float* rb = routed + (size_t)b * 4 * 32 * 32;
        float* recb = rec + (size_t)b * 3 * 65536;
        wsplit_all_kernel<<<7488, 256, 0, stream>>>(Wd1, Wc1, Wd2, Wc2, Wd3, Wc3,
                                                    wspD1, wspC1, wspD2, wspC2, wspD3, slotC3);
        // Wi: routed(fp32) -> h0 A-format in U[0,1M)
        conv3x3<4, 256, 32, 32, 4, 16, 0, 1><<<dim3(16, 4, 1), 256, 0, stream>>>(rb, Wi, bi, Uu);
        // d1: U h0A -> V a1A (4M)
        deconvM<256, 256, 32, 32><<<dim3(1, 8, 8), 256, 0, stream>>>(Uu, wspD1, bd1, Vp);
        // c1: V a1A -> U A (4M)
        convM<256, 256, 64, 64, 1, 1><<<dim3(2, 16, 4), 256, 0, stream>>>(Vp, wspC1, bc1, Uu);
        // d2: U -> V A (8M)
        deconvM<256, 128, 64, 64><<<dim3(2, 16, 4), 256, 0, stream>>>(Uu, wspD2, bd2, Vp);
        // c2: V -> U A (16M)
        convM<128, 128, 128, 128, 1, 1><<<dim3(4, 32, 2), 256, 0, stream>>>(Vp, wspC2, bc2, Uu);
        // d3: U -> V A (32M, fills V)
        deconvM<128, 128, 128, 128><<<dim3(4, 32, 4), 256, 0, stream>>>(Uu, wspD3, bd3, Vp);
        // c3: V -> U fp32 planar (32M, fills U)
        convM<128, 128, 256, 256, 2, 0><<<dim3(8, 32, 2), 256, 0, stream>>>(Vp, slotC3, bc3, U);
        // co: U fp32 -> rec (tanh)
        conv3x3<128, 3, 256, 256, 8, 3, 2, 0><<<dim3(1, 256, 1), 256, 0, stream>>>(U, Wo, bo, recb);
    }
}

// Round 7
// 3102.603 us; speedup vs baseline: 6.5185x; 1.1703x over previous
//
#include <hip/hip_runtime.h>
#include <hip/hip_bf16.h>
#include <cstdint>
#include <cstddef>

// ---------------------------------------------------------------------------
// DVAE forward v6: decoder fully on MFMA split-bf16 (as v5.1), plus:
//  - wsplit hoisted out of the batch loop (1 launch, not 8). Weight slots
//    moved to U+[24M,32M): permanently dead because U's activation footprint
//    is now <=16.8MB (c3 outputs hi-only A-format).
//  - final co conv rewritten as coA: reads c3's bf16-hi A-format directly,
//    weights pre-transposed [co][t][ci] (uniform -> scalar K$ loads, no LDS),
//    3 couts/thread. Replaces the 90us latency-bound fp32 conv3x3.
// Slot map (ws offsets, MiB): D1@24(2.25) C1@26.5(2.25) D2@29(1.125)
//    D3@30.25(0.5625) C2@31(0.5625) wO@31.75(13.5KiB); C3 slot in rec[7] tail.
// ---------------------------------------------------------------------------

#define B 8

typedef __attribute__((ext_vector_type(8)))  short  short8;
typedef __attribute__((ext_vector_type(4)))  short  short4v;
typedef __attribute__((ext_vector_type(16))) float  f32x16;

__device__ inline unsigned short f2bf(float x) {          // RNE f32->bf16
    uint32_t u = __float_as_uint(x);
    uint32_t r = (u + 0x7FFFu + ((u >> 16) & 1u)) >> 16;
    return (unsigned short)r;
}
__device__ inline float bf2f(unsigned short h) {
    return __uint_as_float(((uint32_t)h) << 16);
}

// ---------------- encoder strided conv (Cin=3, Cout=4, k=3, pad=1) ----------
__global__ void enc_conv_kernel(const float* __restrict__ x, const float* __restrict__ w,
                                const float* __restrict__ bias, float* __restrict__ out,
                                int S, int HO) {
    int id = blockIdx.x * 256 + threadIdx.x;
    int total = B * 4 * HO * HO;
    if (id >= total) return;
    int ox = id % HO, oy = (id / HO) % HO, co = (id / (HO * HO)) % 4, b = id / (HO * HO * 4);
    float acc = bias[co];
    for (int ci = 0; ci < 3; ++ci) {
        const float* xp = x + ((size_t)b * 3 + ci) * 65536;
        const float* wp = w + (co * 3 + ci) * 9;
        #pragma unroll
        for (int ky = 0; ky < 3; ++ky) {
            int iy = oy * S - 1 + ky;
            if (iy < 0 || iy >= 256) continue;
            #pragma unroll
            for (int kx = 0; kx < 3; ++kx) {
                int ix = ox * S - 1 + kx;
                if (ix < 0 || ix >= 256) continue;
                acc = fmaf(xp[iy * 256 + ix], wp[ky * 3 + kx], acc);
            }
        }
    }
    out[id] = acc;
}

// ---------------- entropy (KDE), gray fused ----------------
__global__ __launch_bounds__(256) void entropy_kernel(const float* __restrict__ x,
                                                      float* __restrict__ ent) {
    __shared__ float s_patch[256];
    __shared__ float s_red[4];
    int blk = blockIdx.x;
    int b = blk >> 8, rem = blk & 255;
    int py = rem >> 4, px = rem & 15;
    int tid = threadIdx.x;
    int pr = tid >> 4, pc = tid & 15;
    const float* xb = x + (size_t)b * 3 * 65536;
    int p = (py * 16 + pr) * 256 + (px * 16 + pc);
    s_patch[tid] = 0.299f * xb[p] + 0.587f * xb[65536 + p] + 0.114f * xb[2 * 65536 + p];
    __syncthreads();

    float bin = (float)tid * (1.0f / 255.0f);
    float s = 0.f;
    #pragma unroll 8
    for (int q = 0; q < 256; ++q) {
        float t = (s_patch[q] - bin) * 100.0f;
        s += expf(-0.5f * (t * t));
    }
    float pdf = s * (1.0f / 256.0f);

    float r = pdf;
    #pragma unroll
    for (int o = 32; o > 0; o >>= 1) r += __shfl_down(r, o, 64);
    if ((tid & 63) == 0) s_red[tid >> 6] = r;
    __syncthreads();
    float total = s_red[0] + s_red[1] + s_red[2] + s_red[3];
    __syncthreads();

    float p2 = pdf / total;
    p2 = fmaxf(p2, 1e-10f);
    float e = -p2 * log2f(p2);
    #pragma unroll
    for (int o = 32; o > 0; o >>= 1) e += __shfl_down(e, o, 64);
    if ((tid & 63) == 0) s_red[tid >> 6] = e;
    __syncthreads();
    if (tid == 0) ent[blk] = s_red[0] + s_red[1] + s_red[2] + s_red[3];
}

// ---------------- median of 2048 values (bitonic sort) ----------------
__global__ __launch_bounds__(1024) void median_kernel(const float* __restrict__ ent,
                                                      float* __restrict__ thr) {
    __shared__ float s[2048];
    int tid = threadIdx.x;
    s[tid] = ent[tid];
    s[tid + 1024] = ent[tid + 1024];
    __syncthreads();
    for (int k = 2; k <= 2048; k <<= 1) {
        for (int j = k >> 1; j > 0; j >>= 1) {
            int t = tid;
            #pragma unroll 1
            for (int rep = 0; rep < 2; ++rep, t += 1024) {
                int ixj = t ^ j;
                if (ixj > t) {
                    float a = s[t], bb = s[ixj];
                    bool up = ((t & k) == 0);
                    bool sw = up ? (a > bb) : (a < bb);
                    if (sw) { s[t] = bb; s[ixj] = a; }
                }
            }
            __syncthreads();
        }
    }
    if (tid == 0) *thr = 0.5f * (s[1023] + s[1024]);
}

__global__ void grain_kernel(const float* __restrict__ ent, const float* __restrict__ thr,
                             float* __restrict__ grain) {
    int id = blockIdx.x * 256 + threadIdx.x;
    if (id >= 2048) return;
    grain[id] = (ent[id] > *thr) ? 1.0f : 0.0f;
}

__global__ void route_kernel(const float* __restrict__ latf, const float* __restrict__ latc,
                             const float* __restrict__ grain, float* __restrict__ routed) {
    int id = blockIdx.x * 256 + threadIdx.x;
    if (id >= B * 4 * 32 * 32) return;
    int xx = id & 31, yy = (id >> 5) & 31, c = (id >> 10) & 3, b = id >> 12;
    float g = grain[b * 256 + (yy >> 1) * 16 + (xx >> 1)];
    float cu = latc[((b * 4 + c) * 16 + (yy >> 1)) * 16 + (xx >> 1)];
    routed[id] = g * latf[id] + (1.0f - g) * cu;
}

// ---------------- fp32 conv3x3 (Wi -> A-format) ----------------
template<int CIN, int COUT, int H, int W, int CI_BLK, int CO_BLK>
__global__ __launch_bounds__(256) void conv3x3A(const float* __restrict__ in,
                                                const float* __restrict__ wgt,
                                                const float* __restrict__ bias,
                                                unsigned short* __restrict__ outA) {
    constexpr int TW = W / 16;
    __shared__ float s_in[CI_BLK][18][18];
    __shared__ float s_w[CI_BLK][9][CO_BLK];
    const int tid = threadIdx.x;
    const int lx = tid & 15, ly = tid >> 4;
    const int co0 = blockIdx.x * CO_BLK;
    const int tile = blockIdx.y;
    const int tx0 = (tile % TW) * 16, ty0 = (tile / TW) * 16;
    const int ox = tx0 + lx, oy = ty0 + ly;

    float acc[CO_BLK];
    #pragma unroll
    for (int i = 0; i < CO_BLK; ++i) acc[i] = bias[co0 + i];

    for (int ci0 = 0; ci0 < CIN; ci0 += CI_BLK) {
        for (int idx = tid; idx < CI_BLK * 324; idx += 256) {
            int ci = idx / 324, rm = idx % 324;
            int r = rm / 18, c = rm % 18;
            int iy = ty0 - 1 + r, ix = tx0 - 1 + c;
            float v = 0.f;
            if (iy >= 0 && iy < H && ix >= 0 && ix < W)
                v = in[((size_t)(ci0 + ci) * H + iy) * W + ix];
            s_in[ci][r][c] = v;
        }
        for (int idx = tid; idx < CI_BLK * 9 * CO_BLK; idx += 256) {
            int ci = idx / (9 * CO_BLK), rm = idx % (9 * CO_BLK);
            int k = rm / CO_BLK, co = rm % CO_BLK;
            s_w[ci][k][co] = wgt[((size_t)(co0 + co) * CIN + ci0 + ci) * 9 + k];
        }
        __syncthreads();
        #pragma unroll
        for (int ci = 0; ci < CI_BLK; ++ci) {
            float v[9];
            #pragma unroll
            for (int ky = 0; ky < 3; ++ky)
                #pragma unroll
                for (int kx = 0; kx < 3; ++kx)
                    v[ky * 3 + kx] = s_in[ci][ly + ky][lx + kx];
            #pragma unroll
            for (int k = 0; k < 9; ++k) {
                #pragma unroll
                for (int c4 = 0; c4 < CO_BLK / 4; ++c4) {
                    const float4 w4 = *reinterpret_cast<const float4*>(&s_w[ci][k][c4 * 4]);
                    acc[c4 * 4 + 0] = fmaf(v[k], w4.x, acc[c4 * 4 + 0]);
                    acc[c4 * 4 + 1] = fmaf(v[k], w4.y, acc[c4 * 4 + 1]);
                    acc[c4 * 4 + 2] = fmaf(v[k], w4.z, acc[c4 * 4 + 2]);
                    acc[c4 * 4 + 3] = fmaf(v[k], w4.w, acc[c4 * 4 + 3]);
                }
            }
        }
        __syncthreads();
    }
    #pragma unroll
    for (int co = 0; co < CO_BLK; ++co) {
        float v = acc[co];
        int c = co0 + co;
        unsigned short h = f2bf(v);
        unsigned short l = f2bf(v - bf2f(h));
        size_t a = ((size_t)(c >> 4) * H * W + (size_t)oy * W + ox) * 16 + (c & 15);
        outA[a] = h;
        outA[a + (size_t)H * W * COUT] = l;
    }
}

// ---------------- fused weight pre-split (runs ONCE) ------------------------
// conv slot:   [cob(64co)][ch][hl][kh][t][co64][ci8]
// deconv slot: [cob(32co)][ch][hl][kh][t][co32][ci8]
// wO slot:     fp32 [co][t][ci]  (for coA scalar loads)
__device__ inline void wsplit_conv_one(const float* __restrict__ w, unsigned short* dst,
                                       int CIN, int idx) {
    int t = idx % 9;
    int ci = (idx / 9) % CIN;
    int co = idx / (9 * CIN);
    float x = w[idx];
    unsigned short h = f2bf(x);
    unsigned short l = f2bf(x - bf2f(h));
    int CH = CIN >> 4;
    int cob = co >> 6, col = co & 63;
    int ch = ci >> 4, kh = (ci >> 3) & 1, ci8 = ci & 7;
    size_t base = (size_t)(cob * CH + ch) * 18432 + (size_t)((kh * 9 + t) * 512) + col * 8 + ci8;
    dst[base] = h;
    dst[base + 9216] = l;
}
__device__ inline void wsplit_deconv_one(const float* __restrict__ w, unsigned short* dst,
                                         int CIN, int COUT, int idx) {
    int t = idx % 9;
    int co = (idx / 9) % COUT;
    int ci = idx / (9 * COUT);
    float x = w[idx];           // w[ci][co][t]
    unsigned short h = f2bf(x);
    unsigned short l = f2bf(x - bf2f(h));
    int CH = CIN >> 4;
    int cob = co >> 5, col = co & 31;
    int ch = ci >> 4, kh = (ci >> 3) & 1, ci8 = ci & 7;
    size_t base = (size_t)(cob * CH + ch) * 9216 + (size_t)((kh * 9 + t) * 256) + col * 8 + ci8;
    dst[base] = h;
    dst[base + 4608] = l;
}
__global__ void wsplit_all_kernel(const float* Wd1, const float* Wc1, const float* Wd2,
                                  const float* Wc2, const float* Wd3, const float* Wc3,
                                  const float* Wo,
                                  unsigned short* pD1, unsigned short* pC1,
                                  unsigned short* pD2, unsigned short* pC2,
                                  unsigned short* pD3, unsigned short* pC3,
                                  float* pO) {
    int gb = blockIdx.x, tid = threadIdx.x;
    if      (gb < 2304) wsplit_deconv_one(Wd1, pD1, 256, 256, gb * 256 + tid);
    else if (gb < 4608) wsplit_conv_one  (Wc1, pC1, 256, (gb - 2304) * 256 + tid);
    else if (gb < 5760) wsplit_deconv_one(Wd2, pD2, 256, 128, (gb - 4608) * 256 + tid);
    else if (gb < 6336) wsplit_conv_one  (Wc2, pC2, 128, (gb - 5760) * 256 + tid);
    else if (gb < 6912) wsplit_deconv_one(Wd3, pD3, 128, 128, (gb - 6336) * 256 + tid);
    else if (gb < 7488) wsplit_conv_one  (Wc3, pC3, 128, (gb - 6912) * 256 + tid);
    else {
        int idx = (gb - 7488) * 256 + tid;           // Wo[3][128][9] -> pO[3][9][128]
        if (idx < 3456) {
            int co = idx / 1152, r = idx % 1152, ci = r / 9, t = r % 9;
            pO[(co * 9 + t) * 128 + ci] = Wo[(co * 128 + ci) * 9 + t];
        }
    }
}

// ---------------- MFMA conv3x3 (split-bf16 3-term) -------------------------
// In: A-format bf16 hi/lo. OUTM 1: A-format hi/lo + ReLU. OUTM 2: hi-only.
template<int CIN, int COUT, int H, int W, int P, int OUTM>
__global__ __launch_bounds__(256) void convM(const unsigned short* __restrict__ xA,
                                             const unsigned short* __restrict__ wsp,
                                             const float* __restrict__ bias,
                                             unsigned short* __restrict__ outU) {
    constexpr int R = 4 * P;
    constexpr int CH = CIN / 16;
    constexpr size_t LIN = (size_t)H * W * CIN;
    constexpr size_t LOUT = (size_t)H * W * COUT;
    __shared__ __align__(16) unsigned short sX[2][2][R + 2][34][8];
    __shared__ __align__(16) unsigned short sW[2][2][9][64][8];
    const int tid = threadIdx.x;
    const int lane = tid & 63, wv = tid >> 6;
    const int n = lane & 31, kh = lane >> 5;
    const int x0 = blockIdx.x * 32;
    const int y0 = blockIdx.y * R;
    const int cob = blockIdx.z;
    const unsigned short* wblk = wsp + (size_t)cob * CH * 18432;

    f32x16 acc[P][2];
    #pragma unroll
    for (int p = 0; p < P; ++p) { acc[p][0] = (f32x16)0.0f; acc[p][1] = (f32x16)0.0f; }

    for (int ch = 0; ch < CH; ++ch) {
        __syncthreads();
        for (int i = tid; i < (R + 2) * 34 * 4; i += 256) {
            int sub = i & 3, hl = sub >> 1, khs = sub & 1;
            int cell = i >> 2, row = cell / 34, col = cell - row * 34;
            int gy = y0 - 1 + row, gx = x0 - 1 + col;
            uint4 v = make_uint4(0u, 0u, 0u, 0u);
            if (gy >= 0 && gy < H && gx >= 0 && gx < W)
                v = *(const uint4*)&xA[(size_t)hl * LIN +
                        ((size_t)(ch * H + gy) * W + gx) * 16 + khs * 8];
            *(uint4*)&sX[hl][khs][row][col][0] = v;
        }
        {
            const uint4* src = (const uint4*)(wblk + (size_t)ch * 18432);
            uint4* dst = (uint4*)&sW[0][0][0][0][0];
            constexpr int NW = (int)(sizeof(sW) / 16);
            for (int i = tid; i < NW; i += 256) dst[i] = src[i];
        }
        __syncthreads();
        #pragma unroll
        for (int t = 0; t < 9; ++t) {
            const int ky = t / 3, kx = t % 3;
            short8 wh0 = *(const short8*)&sW[0][kh][t][n][0];
            short8 wh1 = *(const short8*)&sW[0][kh][t][32 + n][0];
            short8 wl0 = *(const short8*)&sW[1][kh][t][n][0];
            short8 wl1 = *(const short8*)&sW[1][kh][t][32 + n][0];
            #pragma unroll
            for (int p = 0; p < P; ++p) {
                const int row = wv * P + p + ky;
                short8 xh = *(const short8*)&sX[0][kh][row][n + kx][0];
                short8 xl = *(const short8*)&sX[1][kh][row][n + kx][0];
                acc[p][0] = __builtin_amdgcn_mfma_f32_32x32x16_bf16(wh0, xh, acc[p][0], 0, 0, 0);
                acc[p][1] = __builtin_amdgcn_mfma_f32_32x32x16_bf16(wh1, xh, acc[p][1], 0, 0, 0);
                acc[p][0] = __builtin_amdgcn_mfma_f32_32x32x16_bf16(wh0, xl, acc[p][0], 0, 0, 0);
                acc[p][1] = __builtin_amdgcn_mfma_f32_32x32x16_bf16(wh1, xl, acc[p][1], 0, 0, 0);
                acc[p][0] = __builtin_amdgcn_mfma_f32_32x32x16_bf16(wl0, xh, acc[p][0], 0, 0, 0);
                acc[p][1] = __builtin_amdgcn_mfma_f32_32x32x16_bf16(wl1, xh, acc[p][1], 0, 0, 0);
            }
        }
    }
    #pragma unroll
    for (int p = 0; p < P; ++p) {
        const int y = y0 + wv * P + p;
        #pragma unroll
        for (int cg = 0; cg < 2; ++cg) {
            #pragma unroll
            for (int grp = 0; grp < 4; ++grp) {
                int co4 = cob * 64 + cg * 32 + grp * 8 + kh * 4;
                short4v h4, l4;
                #pragma unroll
                for (int j = 0; j < 4; ++j) {
                    float v = fmaxf(acc[p][cg][grp * 4 + j] + bias[co4 + j], 0.f);
                    unsigned short h = f2bf(v);
                    h4[j] = (short)h;
                    l4[j] = (short)f2bf(v - bf2f(h));
                }
                size_t a = ((size_t)(co4 >> 4) * H * W + (size_t)y * W + (x0 + n)) * 16
                         + (co4 & 15);
                *(short4v*)&outU[a] = h4;
                if constexpr (OUTM == 1) *(short4v*)&outU[a + LOUT] = l4;
            }
        }
    }
}

// ---------------- MFMA deconv (parity-split, split-bf16 3-term) -------------
template<int CIN, int COUT, int HIN, int WIN>
__global__ __launch_bounds__(256) void deconvM(const unsigned short* __restrict__ xA,
                                               const unsigned short* __restrict__ wsp,
                                               const float* __restrict__ bias,
                                               unsigned short* __restrict__ outA) {
    constexpr int HO = 2 * HIN, WO = 2 * WIN;
    constexpr int CH = CIN / 16;
    constexpr size_t LIN = (size_t)HIN * WIN * CIN;
    constexpr size_t LOUT = (size_t)HO * WO * COUT;
    __shared__ __align__(16) unsigned short sX[2][2][5][33][8];
    __shared__ __align__(16) unsigned short sW[2][2][9][32][8];
    const int tid = threadIdx.x;
    const int lane = tid & 63, wv = tid >> 6;
    const int n = lane & 31, kh = lane >> 5;
    const int x0 = blockIdx.x * 32;
    const int y0q = blockIdx.y * 4;
    const int cog = blockIdx.z;
    const unsigned short* wblk = wsp + (size_t)cog * CH * 9216;

    f32x16 acc[4];
    #pragma unroll
    for (int d = 0; d < 4; ++d) acc[d] = (f32x16)0.0f;

    for (int ch = 0; ch < CH; ++ch) {
        __syncthreads();
        for (int i = tid; i < 5 * 33 * 4; i += 256) {
            int sub = i & 3, hl = sub >> 1, khs = sub & 1;
            int cell = i >> 2, row = cell / 33, col = cell - row * 33;
            int gy = y0q + row, gx = x0 + col;
            uint4 v = make_uint4(0u, 0u, 0u, 0u);
            if (gy < HIN && gx < WIN)
                v = *(const uint4*)&xA[(size_t)hl * LIN +
                        ((size_t)(ch * HIN + gy) * WIN + gx) * 16 + khs * 8];
            *(uint4*)&sX[hl][khs][row][col][0] = v;
        }
        {
            const uint4* src = (const uint4*)(wblk + (size_t)ch * 9216);
            uint4* dst = (uint4*)&sW[0][0][0][0][0];
            constexpr int NW = (int)(sizeof(sW) / 16);
            for (int i = tid; i < NW; i += 256) dst[i] = src[i];
        }
        __syncthreads();
        short8 xf[2][2][2];     // [hl][dy][dx]
        #pragma unroll
        for (int dy = 0; dy < 2; ++dy)
            #pragma unroll
            for (int dx = 0; dx < 2; ++dx) {
                xf[0][dy][dx] = *(const short8*)&sX[0][kh][wv + dy][n + dx][0];
                xf[1][dy][dx] = *(const short8*)&sX[1][kh][wv + dy][n + dx][0];
            }
        constexpr int SRC[9] = {3, 2, 2, 1, 0, 0, 1, 0, 0};
        constexpr int DST[9] = {3, 2, 3, 1, 0, 1, 3, 2, 3};
        #pragma unroll
        for (int t = 0; t < 9; ++t) {
            short8 wh = *(const short8*)&sW[0][kh][t][n][0];
            short8 wl = *(const short8*)&sW[1][kh][t][n][0];
            const int dy = SRC[t] >> 1, dx = SRC[t] & 1, d = DST[t];
            acc[d] = __builtin_amdgcn_mfma_f32_32x32x16_bf16(wh, xf[0][dy][dx], acc[d], 0, 0, 0);
            acc[d] = __builtin_amdgcn_mfma_f32_32x32x16_bf16(wh, xf[1][dy][dx], acc[d], 0, 0, 0);
            acc[d] = __builtin_amdgcn_mfma_f32_32x32x16_bf16(wl, xf[0][dy][dx], acc[d], 0, 0, 0);
        }
    }
    const int oyb = 2 * (y0q + wv), oxb = 2 * (x0 + n);
    #pragma unroll
    for (int pos = 0; pos < 4; ++pos) {
        const int oy = oyb + (pos >> 1), ox = oxb + (pos & 1);
        #pragma unroll
        for (int grp = 0; grp < 4; ++grp) {
            int co4 = cog * 32 + grp * 8 + kh * 4;
            short4v h4, l4;
            #pragma unroll
            for (int j = 0; j < 4; ++j) {
                float v = fmaxf(acc[pos][grp * 4 + j] + bias[co4 + j], 0.f);
                unsigned short h = f2bf(v);
                h4[j] = (short)h;
                l4[j] = (short)f2bf(v - bf2f(h));
            }
            size_t a = ((size_t)(co4 >> 4) * HO * WO + (size_t)oy * WO + ox) * 16 + (co4 & 15);
            *(short4v*)&outA[a] = h4;
            *(short4v*)&outA[a + LOUT] = l4;
        }
    }
}

// ---------------- final conv (128->3) + tanh, from bf16-hi A-format ----------
// Weights via wO[co][t][ci] (uniform index -> scalar K$ loads). No LDS.
__global__ __launch_bounds__(256) void coA_kernel(const unsigned short* __restrict__ xA,
                                                  const float* __restrict__ wO,
                                                  const float* __restrict__ bo,
                                                  float* __restrict__ rec) {
    const int tid = threadIdx.x;
    const int lx = tid & 15, ly = tid >> 4;
    const int tx0 = (blockIdx.x & 15) * 16, ty0 = (blockIdx.x >> 4) * 16;
    const int ox = tx0 + lx, oy = ty0 + ly;
    float a0 = bo[0], a1 = bo[1], a2 = bo[2];
    for (int ch = 0; ch < 8; ++ch) {
        unsigned short cs[9][16];
        #pragma unroll
        for (int t = 0; t < 9; ++t) {
            const int gy = oy - 1 + t / 3, gx = ox - 1 + t % 3;
            uint4 v0 = make_uint4(0u, 0u, 0u, 0u), v1 = make_uint4(0u, 0u, 0u, 0u);
            if (gy >= 0 && gy < 256 && gx >= 0 && gx < 256) {
                const uint4* p = (const uint4*)&xA[((size_t)(ch * 256 + gy) * 256 + gx) * 16];
                v0 = p[0]; v1 = p[1];
            }
            *(uint4*)&cs[t][0] = v0;
            *(uint4*)&cs[t][8] = v1;
        }
        #pragma unroll
        for (int t = 0; t < 9; ++t) {
            const float* w0 = &wO[(0 * 9 + t) * 128 + ch * 16];
            const float* w1 = &wO[(1 * 9 + t) * 128 + ch * 16];
            const float* w2 = &wO[(2 * 9 + t) * 128 + ch * 16];
            #pragma unroll
            for (int j = 0; j < 16; ++j) {
                float v = bf2f(cs[t][j]);
                a0 = fmaf(v, w0[j], a0);
                a1 = fmaf(v, w1[j], a1);
                a2 = fmaf(v, w2[j], a2);
            }
        }
    }
    const int px = oy * 256 + ox;
    rec[px]                = tanhf(a0);
    rec[65536 + px]        = tanhf(a1);
    rec[2 * 65536 + px]    = tanhf(a2);
}

// ---------------------------------------------------------------------------
extern "C" void kernel_launch(void* const* d_in, const int* in_sizes, int n_in,
                              void* d_out, int out_size, void* d_ws, size_t ws_size,
                              hipStream_t stream) {
    const float* x   = (const float*)d_in[0];
    const float* We0 = (const float*)d_in[1];  const float* be0 = (const float*)d_in[2];
    const float* We1 = (const float*)d_in[3];  const float* be1 = (const float*)d_in[4];
    const float* Wi  = (const float*)d_in[5];  const float* bi  = (const float*)d_in[6];
    const float* Wd1 = (const float*)d_in[7];  const float* bd1 = (const float*)d_in[8];
    const float* Wc1 = (const float*)d_in[9];  const float* bc1 = (const float*)d_in[10];
    const float* Wd2 = (const float*)d_in[11]; const float* bd2 = (const float*)d_in[12];
    const float* Wc2 = (const float*)d_in[13]; const float* bc2 = (const float*)d_in[14];
    const float* Wd3 = (const float*)d_in[15]; const float* bd3 = (const float*)d_in[16];
    const float* Wc3 = (const float*)d_in[17]; const float* bc3 = (const float*)d_in[18];
    const float* Wo  = (const float*)d_in[19]; const float* bo  = (const float*)d_in[20];

    float* out    = (float*)d_out;
    float* rec    = out;               // [8,3,256,256]
    float* routed = out + 1572864;     // [8,4,32,32]
    float* grain  = out + 1605632;     // [8,16,16]
    float* ent    = out + 1607680;     // [8,16,16]

    // latent scratch in rec region (dead before first rec write)
    float* latf = out;                 // 32768 floats
    float* latc = out + 32768;         // 8192 floats
    float* thr  = out + 40960;         // 1 float
    // Wc3 split slot in rec[7] tail: written once; last read by c3(7), then
    // overwritten by coA(7) (stream-serial).
    unsigned short* slotC3 = (unsigned short*)(out + 1425408);

    // workspace: U activations [0,16.8M) max; slots [24M,32M) never clobbered
    // (Wi 1M, c1 4M, c2 8M, c3-hi 16.8M are the only U writes);
    // V = [32M, 65.6M) (d3 hi/lo fills it).
    char* ws8 = (char*)d_ws;
    unsigned short* Uu    = (unsigned short*)ws8;
    unsigned short* Vp    = (unsigned short*)(ws8 + (size_t)32 * 1024 * 1024);
    unsigned short* wspD1 = (unsigned short*)(ws8 + (size_t)24 * 1024 * 1024);
    unsigned short* wspC1 = (unsigned short*)(ws8 + (size_t)26 * 1024 * 1024 + 512 * 1024);
    unsigned short* wspD2 = (unsigned short*)(ws8 + (size_t)29 * 1024 * 1024);
    unsigned short* wspD3 = (unsigned short*)(ws8 + (size_t)30 * 1024 * 1024 + 256 * 1024);
    unsigned short* wspC2 = (unsigned short*)(ws8 + (size_t)31 * 1024 * 1024);
    float*          wspO  = (float*)(ws8 + (size_t)31 * 1024 * 1024 + 768 * 1024);

    // --- entropy / routing path ---
    enc_conv_kernel<<<128, 256, 0, stream>>>(x, We0, be0, latf, 8, 32);
    enc_conv_kernel<<<32, 256, 0, stream>>>(x, We1, be1, latc, 16, 16);
    entropy_kernel<<<2048, 256, 0, stream>>>(x, ent);
    median_kernel<<<1, 1024, 0, stream>>>(ent, thr);
    grain_kernel<<<8, 256, 0, stream>>>(ent, thr, grain);
    route_kernel<<<128, 256, 0, stream>>>(latf, latc, grain, routed);

    // --- weight pre-split: ONCE (slots persist across batches) ---
    wsplit_all_kernel<<<7502, 256, 0, stream>>>(Wd1, Wc1, Wd2, Wc2, Wd3, Wc3, Wo,
                                                wspD1, wspC1, wspD2, wspC2, wspD3, slotC3,
                                                wspO);

    // --- decoder, per batch ---
    for (int b = 0; b < B; ++b) {
        const float* rb = routed + (size_t)b * 4 * 32 * 32;
        float* recb = rec + (size_t)b * 3 * 65536;
        // Wi: routed(fp32) -> h0 A-format hi/lo in U[0,1M)
        conv3x3A<4, 256, 32, 32, 4, 16><<<dim3(16, 4, 1), 256, 0, stream>>>(rb, Wi, bi, Uu);
        // d1: U -> V A (4M)
        deconvM<256, 256, 32, 32><<<dim3(1, 8, 8), 256, 0, stream>>>(Uu, wspD1, bd1, Vp);
        // c1: V -> U A (4M)
        convM<256, 256, 64, 64, 1, 1><<<dim3(2, 16, 4), 256, 0, stream>>>(Vp, wspC1, bc1, Uu);
        // d2: U -> V A (8M)
        deconvM<256, 128, 64, 64><<<dim3(2, 16, 4), 256, 0, stream>>>(Uu, wspD2, bd2, Vp);
        // c2: V -> U A (8M)
        convM<128, 128, 128, 128, 1, 1><<<dim3(4, 32, 2), 256, 0, stream>>>(Vp, wspC2, bc2, Uu);
        // d3: U -> V A hi/lo (33.6M, fills V)
        deconvM<128, 128, 128, 128><<<dim3(4, 32, 4), 256, 0, stream>>>(Uu, wspD3, bd3, Vp);
        // c3: V -> U A hi-only (16.8M)
        convM<128, 128, 256, 256, 2, 2><<<dim3(8, 32, 2), 256, 0, stream>>>(Vp, slotC3, bc3, Uu);
        // co: U(hi A) -> rec fp32 + tanh
        coA_kernel<<<256, 256, 0, stream>>>(Uu, wspO, bo, recb);
    }
}

// Round 8
// 2656.062 us; speedup vs baseline: 7.6144x; 1.1681x over previous
//
#include <hip/hip_runtime.h>
#include <hip/hip_bf16.h>
#include <cstdint>
#include <cstddef>

// ---------------------------------------------------------------------------
// DVAE forward v7: v6 + register-staged async pipeline in convM/deconvM.
// Round-7 diagnosis: convM/deconvM were staging-latency-bound (MfmaUtil 6.5%,
// 28x above MFMA floor) — the strided staging loop serialized ~12 global
// round-trips per ci-chunk. Now: LOADS(ch)->regs (all issued, one wait),
// WRITE->LDS, sync, LOADS(ch+1) issued, COMPUTE(ch) — latency hides under
// MFMA + barrier. Plus NCG template: c1/c2 use 32-cout blocks (256/512
// blocks -> full chip). Weight slots re-laid at 32-cout granularity
// ([cob32][ch][hl][kh][t][co32][ci8] — conv slot layout == deconv's).
// Slot offsets/footprints unchanged from v6.
// ---------------------------------------------------------------------------

#define B 8

typedef __attribute__((ext_vector_type(8)))  short  short8;
typedef __attribute__((ext_vector_type(4)))  short  short4v;
typedef __attribute__((ext_vector_type(16))) float  f32x16;

__device__ inline unsigned short f2bf(float x) {          // RNE f32->bf16
    uint32_t u = __float_as_uint(x);
    uint32_t r = (u + 0x7FFFu + ((u >> 16) & 1u)) >> 16;
    return (unsigned short)r;
}
__device__ inline float bf2f(unsigned short h) {
    return __uint_as_float(((uint32_t)h) << 16);
}

// ---------------- encoder strided conv (Cin=3, Cout=4, k=3, pad=1) ----------
__global__ void enc_conv_kernel(const float* __restrict__ x, const float* __restrict__ w,
                                const float* __restrict__ bias, float* __restrict__ out,
                                int S, int HO) {
    int id = blockIdx.x * 256 + threadIdx.x;
    int total = B * 4 * HO * HO;
    if (id >= total) return;
    int ox = id % HO, oy = (id / HO) % HO, co = (id / (HO * HO)) % 4, b = id / (HO * HO * 4);
    float acc = bias[co];
    for (int ci = 0; ci < 3; ++ci) {
        const float* xp = x + ((size_t)b * 3 + ci) * 65536;
        const float* wp = w + (co * 3 + ci) * 9;
        #pragma unroll
        for (int ky = 0; ky < 3; ++ky) {
            int iy = oy * S - 1 + ky;
            if (iy < 0 || iy >= 256) continue;
            #pragma unroll
            for (int kx = 0; kx < 3; ++kx) {
                int ix = ox * S - 1 + kx;
                if (ix < 0 || ix >= 256) continue;
                acc = fmaf(xp[iy * 256 + ix], wp[ky * 3 + kx], acc);
            }
        }
    }
    out[id] = acc;
}

// ---------------- entropy (KDE), gray fused ----------------
__global__ __launch_bounds__(256) void entropy_kernel(const float* __restrict__ x,
                                                      float* __restrict__ ent) {
    __shared__ float s_patch[256];
    __shared__ float s_red[4];
    int blk = blockIdx.x;
    int b = blk >> 8, rem = blk & 255;
    int py = rem >> 4, px = rem & 15;
    int tid = threadIdx.x;
    int pr = tid >> 4, pc = tid & 15;
    const float* xb = x + (size_t)b * 3 * 65536;
    int p = (py * 16 + pr) * 256 + (px * 16 + pc);
    s_patch[tid] = 0.299f * xb[p] + 0.587f * xb[65536 + p] + 0.114f * xb[2 * 65536 + p];
    __syncthreads();

    float bin = (float)tid * (1.0f / 255.0f);
    float s = 0.f;
    #pragma unroll 8
    for (int q = 0; q < 256; ++q) {
        float t = (s_patch[q] - bin) * 100.0f;
        s += expf(-0.5f * (t * t));
    }
    float pdf = s * (1.0f / 256.0f);

    float r = pdf;
    #pragma unroll
    for (int o = 32; o > 0; o >>= 1) r += __shfl_down(r, o, 64);
    if ((tid & 63) == 0) s_red[tid >> 6] = r;
    __syncthreads();
    float total = s_red[0] + s_red[1] + s_red[2] + s_red[3];
    __syncthreads();

    float p2 = pdf / total;
    p2 = fmaxf(p2, 1e-10f);
    float e = -p2 * log2f(p2);
    #pragma unroll
    for (int o = 32; o > 0; o >>= 1) e += __shfl_down(e, o, 64);
    if ((tid & 63) == 0) s_red[tid >> 6] = e;
    __syncthreads();
    if (tid == 0) ent[blk] = s_red[0] + s_red[1] + s_red[2] + s_red[3];
}

// ---------------- median of 2048 values (bitonic sort) ----------------
__global__ __launch_bounds__(1024) void median_kernel(const float* __restrict__ ent,
                                                      float* __restrict__ thr) {
    __shared__ float s[2048];
    int tid = threadIdx.x;
    s[tid] = ent[tid];
    s[tid + 1024] = ent[tid + 1024];
    __syncthreads();
    for (int k = 2; k <= 2048; k <<= 1) {
        for (int j = k >> 1; j > 0; j >>= 1) {
            int t = tid;
            #pragma unroll 1
            for (int rep = 0; rep < 2; ++rep, t += 1024) {
                int ixj = t ^ j;
                if (ixj > t) {
                    float a = s[t], bb = s[ixj];
                    bool up = ((t & k) == 0);
                    bool sw = up ? (a > bb) : (a < bb);
                    if (sw) { s[t] = bb; s[ixj] = a; }
                }
            }
            __syncthreads();
        }
    }
    if (tid == 0) *thr = 0.5f * (s[1023] + s[1024]);
}

__global__ void grain_kernel(const float* __restrict__ ent, const float* __restrict__ thr,
                             float* __restrict__ grain) {
    int id = blockIdx.x * 256 + threadIdx.x;
    if (id >= 2048) return;
    grain[id] = (ent[id] > *thr) ? 1.0f : 0.0f;
}

__global__ void route_kernel(const float* __restrict__ latf, const float* __restrict__ latc,
                             const float* __restrict__ grain, float* __restrict__ routed) {
    int id = blockIdx.x * 256 + threadIdx.x;
    if (id >= B * 4 * 32 * 32) return;
    int xx = id & 31, yy = (id >> 5) & 31, c = (id >> 10) & 3, b = id >> 12;
    float g = grain[b * 256 + (yy >> 1) * 16 + (xx >> 1)];
    float cu = latc[((b * 4 + c) * 16 + (yy >> 1)) * 16 + (xx >> 1)];
    routed[id] = g * latf[id] + (1.0f - g) * cu;
}

// ---------------- fp32 conv3x3 (Wi -> A-format) ----------------
template<int CIN, int COUT, int H, int W, int CI_BLK, int CO_BLK>
__global__ __launch_bounds__(256) void conv3x3A(const float* __restrict__ in,
                                                const float* __restrict__ wgt,
                                                const float* __restrict__ bias,
                                                unsigned short* __restrict__ outA) {
    constexpr int TW = W / 16;
    __shared__ float s_in[CI_BLK][18][18];
    __shared__ float s_w[CI_BLK][9][CO_BLK];
    const int tid = threadIdx.x;
    const int lx = tid & 15, ly = tid >> 4;
    const int co0 = blockIdx.x * CO_BLK;
    const int tile = blockIdx.y;
    const int tx0 = (tile % TW) * 16, ty0 = (tile / TW) * 16;
    const int ox = tx0 + lx, oy = ty0 + ly;

    float acc[CO_BLK];
    #pragma unroll
    for (int i = 0; i < CO_BLK; ++i) acc[i] = bias[co0 + i];

    for (int ci0 = 0; ci0 < CIN; ci0 += CI_BLK) {
        for (int idx = tid; idx < CI_BLK * 324; idx += 256) {
            int ci = idx / 324, rm = idx % 324;
            int r = rm / 18, c = rm % 18;
            int iy = ty0 - 1 + r, ix = tx0 - 1 + c;
            float v = 0.f;
            if (iy >= 0 && iy < H && ix >= 0 && ix < W)
                v = in[((size_t)(ci0 + ci) * H + iy) * W + ix];
            s_in[ci][r][c] = v;
        }
        for (int idx = tid; idx < CI_BLK * 9 * CO_BLK; idx += 256) {
            int ci = idx / (9 * CO_BLK), rm = idx % (9 * CO_BLK);
            int k = rm / CO_BLK, co = rm % CO_BLK;
            s_w[ci][k][co] = wgt[((size_t)(co0 + co) * CIN + ci0 + ci) * 9 + k];
        }
        __syncthreads();
        #pragma unroll
        for (int ci = 0; ci < CI_BLK; ++ci) {
            float v[9];
            #pragma unroll
            for (int ky = 0; ky < 3; ++ky)
                #pragma unroll
                for (int kx = 0; kx < 3; ++kx)
                    v[ky * 3 + kx] = s_in[ci][ly + ky][lx + kx];
            #pragma unroll
            for (int k = 0; k < 9; ++k) {
                #pragma unroll
                for (int c4 = 0; c4 < CO_BLK / 4; ++c4) {
                    const float4 w4 = *reinterpret_cast<const float4*>(&s_w[ci][k][c4 * 4]);
                    acc[c4 * 4 + 0] = fmaf(v[k], w4.x, acc[c4 * 4 + 0]);
                    acc[c4 * 4 + 1] = fmaf(v[k], w4.y, acc[c4 * 4 + 1]);
                    acc[c4 * 4 + 2] = fmaf(v[k], w4.z, acc[c4 * 4 + 2]);
                    acc[c4 * 4 + 3] = fmaf(v[k], w4.w, acc[c4 * 4 + 3]);
                }
            }
        }
        __syncthreads();
    }
    #pragma unroll
    for (int co = 0; co < CO_BLK; ++co) {
        float v = acc[co];
        int c = co0 + co;
        unsigned short h = f2bf(v);
        unsigned short l = f2bf(v - bf2f(h));
        size_t a = ((size_t)(c >> 4) * H * W + (size_t)oy * W + ox) * 16 + (c & 15);
        outA[a] = h;
        outA[a + (size_t)H * W * COUT] = l;
    }
}

// ---------------- fused weight pre-split (runs ONCE) ------------------------
// unified slot layout (conv AND deconv): [cob32][ch][hl][kh][t][co32][ci8]
//   9216 shorts (=1152 uint4) per (cob32,ch); hl stride 4608 shorts.
// wO slot: fp32 [co][t][ci] (for coA scalar loads)
__device__ inline void wsplit_conv_one(const float* __restrict__ w, unsigned short* dst,
                                       int CIN, int idx) {
    int t = idx % 9;
    int ci = (idx / 9) % CIN;
    int co = idx / (9 * CIN);
    float x = w[idx];                   // w[co][ci][t]
    unsigned short h = f2bf(x);
    unsigned short l = f2bf(x - bf2f(h));
    int CH = CIN >> 4;
    int cob = co >> 5, col = co & 31;
    int ch = ci >> 4, kh = (ci >> 3) & 1, ci8 = ci & 7;
    size_t base = (size_t)(cob * CH + ch) * 9216 + (size_t)((kh * 9 + t) * 256) + col * 8 + ci8;
    dst[base] = h;
    dst[base + 4608] = l;
}
__device__ inline void wsplit_deconv_one(const float* __restrict__ w, unsigned short* dst,
                                         int CIN, int COUT, int idx) {
    int t = idx % 9;
    int co = (idx / 9) % COUT;
    int ci = idx / (9 * COUT);
    float x = w[idx];                   // w[ci][co][t]
    unsigned short h = f2bf(x);
    unsigned short l = f2bf(x - bf2f(h));
    int CH = CIN >> 4;
    int cob = co >> 5, col = co & 31;
    int ch = ci >> 4, kh = (ci >> 3) & 1, ci8 = ci & 7;
    size_t base = (size_t)(cob * CH + ch) * 9216 + (size_t)((kh * 9 + t) * 256) + col * 8 + ci8;
    dst[base] = h;
    dst[base + 4608] = l;
}
__global__ void wsplit_all_kernel(const float* Wd1, const float* Wc1, const float* Wd2,
                                  const float* Wc2, const float* Wd3, const float* Wc3,
                                  const float* Wo,
                                  unsigned short* pD1, unsigned short* pC1,
                                  unsigned short* pD2, unsigned short* pC2,
                                  unsigned short* pD3, unsigned short* pC3,
                                  float* pO) {
    int gb = blockIdx.x, tid = threadIdx.x;
    if      (gb < 2304) wsplit_deconv_one(Wd1, pD1, 256, 256, gb * 256 + tid);
    else if (gb < 4608) wsplit_conv_one  (Wc1, pC1, 256, (gb - 2304) * 256 + tid);
    else if (gb < 5760) wsplit_deconv_one(Wd2, pD2, 256, 128, (gb - 4608) * 256 + tid);
    else if (gb < 6336) wsplit_conv_one  (Wc2, pC2, 128, (gb - 5760) * 256 + tid);
    else if (gb < 6912) wsplit_deconv_one(Wd3, pD3, 128, 128, (gb - 6336) * 256 + tid);
    else if (gb < 7488) wsplit_conv_one  (Wc3, pC3, 128, (gb - 6912) * 256 + tid);
    else {
        int idx = (gb - 7488) * 256 + tid;           // Wo[3][128][9] -> pO[3][9][128]
        if (idx < 3456) {
            int co = idx / 1152, r = idx % 1152, ci = r / 9, t = r % 9;
            pO[(co * 9 + t) * 128 + ci] = Wo[(co * 128 + ci) * 9 + t];
        }
    }
}

// ---------------- MFMA conv3x3 (split-bf16 3-term, async reg-staged) --------
// In: A-format bf16 hi/lo. OUTM 1: A-format hi/lo + ReLU. OUTM 2: hi-only.
// NCG = cout-groups (32 couts each) per block. blockIdx.z in units of 32*NCG.
template<int CIN, int COUT, int H, int W, int P, int OUTM, int NCG>
__global__ __launch_bounds__(256) void convM(const unsigned short* __restrict__ xA,
                                             const unsigned short* __restrict__ wsp,
                                             const float* __restrict__ bias,
                                             unsigned short* __restrict__ outU) {
    constexpr int R = 4 * P;
    constexpr int CH = CIN / 16;
    constexpr size_t LIN = (size_t)H * W * CIN;
    constexpr size_t LOUT = (size_t)H * W * COUT;
    constexpr int NXU = (R + 2) * 34 * 4;            // uint4 cells in sX
    constexpr int NLX = (NXU + 255) / 256;
    constexpr int NWU = 1152;                        // uint4 per 32-cout chunk
    constexpr int NLW = (NCG * NWU + 255) / 256;
    __shared__ __align__(16) unsigned short sX[2][2][R + 2][34][8];
    __shared__ __align__(16) unsigned short sW[NCG][2][2][9][32][8];
    const int tid = threadIdx.x;
    const int lane = tid & 63, wv = tid >> 6;
    const int n = lane & 31, kh = lane >> 5;
    const int x0 = blockIdx.x * 32;
    const int y0 = blockIdx.y * R;
    const int cgb = blockIdx.z;
    const uint4* wU4 = (const uint4*)wsp;

    f32x16 acc[P][NCG];
    #pragma unroll
    for (int p = 0; p < P; ++p)
        #pragma unroll
        for (int cg = 0; cg < NCG; ++cg) acc[p][cg] = (f32x16)0.0f;

    uint4 vx[NLX], vw[NLW];
    auto LOADS = [&](int ch) {
        #pragma unroll
        for (int i = 0; i < NLX; ++i) {
            int idx = tid + i * 256;
            int sub = idx & 3, hl = sub >> 1, khs = sub & 1;
            int cell = idx >> 2, row = cell / 34, col = cell - row * 34;
            int gy = y0 - 1 + row, gx = x0 - 1 + col;
            uint4 v = make_uint4(0u, 0u, 0u, 0u);
            if (idx < NXU && gy >= 0 && gy < H && gx >= 0 && gx < W)
                v = *(const uint4*)&xA[(size_t)hl * LIN +
                        ((size_t)(ch * H + gy) * W + gx) * 16 + khs * 8];
            vx[i] = v;
        }
        #pragma unroll
        for (int i = 0; i < NLW; ++i) {
            int idx = tid + i * 256;
            int idc = (idx < NCG * NWU) ? idx : (NCG * NWU - 1);
            int cg = idc / NWU, j = idc - cg * NWU;
            vw[i] = wU4[(size_t)((cgb * NCG + cg) * CH + ch) * NWU + j];
        }
    };
    auto WRITE = [&]() {
        #pragma unroll
        for (int i = 0; i < NLX; ++i) {
            int idx = tid + i * 256;
            if (idx < NXU) {
                int sub = idx & 3, hl = sub >> 1, khs = sub & 1;
                int cell = idx >> 2, row = cell / 34, col = cell - row * 34;
                *(uint4*)&sX[hl][khs][row][col][0] = vx[i];
            }
        }
        uint4* dW = (uint4*)&sW[0][0][0][0][0][0];
        #pragma unroll
        for (int i = 0; i < NLW; ++i) {
            int idx = tid + i * 256;
            if (idx < NCG * NWU) dW[idx] = vw[i];
        }
    };

    LOADS(0);
    for (int ch = 0; ch < CH; ++ch) {
        __syncthreads();                 // prev compute done reading LDS
        WRITE();                         // waits on in-flight loads
        __syncthreads();
        if (ch + 1 < CH) LOADS(ch + 1);  // issue next chunk; hides under MFMA
        #pragma unroll
        for (int t = 0; t < 9; ++t) {
            const int ky = t / 3, kx = t % 3;
            short8 w_h[NCG], w_l[NCG];
            #pragma unroll
            for (int cg = 0; cg < NCG; ++cg) {
                w_h[cg] = *(const short8*)&sW[cg][0][kh][t][n][0];
                w_l[cg] = *(const short8*)&sW[cg][1][kh][t][n][0];
            }
            #pragma unroll
            for (int p = 0; p < P; ++p) {
                const int row = wv * P + p + ky;
                short8 xh = *(const short8*)&sX[0][kh][row][n + kx][0];
                short8 xl = *(const short8*)&sX[1][kh][row][n + kx][0];
                #pragma unroll
                for (int cg = 0; cg < NCG; ++cg) {
                    acc[p][cg] = __builtin_amdgcn_mfma_f32_32x32x16_bf16(w_h[cg], xh, acc[p][cg], 0, 0, 0);
                    acc[p][cg] = __builtin_amdgcn_mfma_f32_32x32x16_bf16(w_h[cg], xl, acc[p][cg], 0, 0, 0);
                    acc[p][cg] = __builtin_amdgcn_mfma_f32_32x32x16_bf16(w_l[cg], xh, acc[p][cg], 0, 0, 0);
                }
            }
        }
    }
    #pragma unroll
    for (int p = 0; p < P; ++p) {
        const int y = y0 + wv * P + p;
        #pragma unroll
        for (int cg = 0; cg < NCG; ++cg) {
            #pragma unroll
            for (int grp = 0; grp < 4; ++grp) {
                int co4 = (cgb * NCG + cg) * 32 + grp * 8 + kh * 4;
                short4v h4, l4;
                #pragma unroll
                for (int j = 0; j < 4; ++j) {
                    float v = fmaxf(acc[p][cg][grp * 4 + j] + bias[co4 + j], 0.f);
                    unsigned short h = f2bf(v);
                    h4[j] = (short)h;
                    l4[j] = (short)f2bf(v - bf2f(h));
                }
                size_t a = ((size_t)(co4 >> 4) * H * W + (size_t)y * W + (x0 + n)) * 16
                         + (co4 & 15);
                *(short4v*)&outU[a] = h4;
                if constexpr (OUTM == 1) *(short4v*)&outU[a + LOUT] = l4;
            }
        }
    }
}

// ---------------- MFMA deconv (parity-split, async reg-staged) --------------
template<int CIN, int COUT, int HIN, int WIN>
__global__ __launch_bounds__(256) void deconvM(const unsigned short* __restrict__ xA,
                                               const unsigned short* __restrict__ wsp,
                                               const float* __restrict__ bias,
                                               unsigned short* __restrict__ outA) {
    constexpr int HO = 2 * HIN, WO = 2 * WIN;
    constexpr int CH = CIN / 16;
    constexpr size_t LIN = (size_t)HIN * WIN * CIN;
    constexpr size_t LOUT = (size_t)HO * WO * COUT;
    constexpr int NXU = 5 * 33 * 4;
    constexpr int NLX = (NXU + 255) / 256;
    constexpr int NWU = 1152;
    constexpr int NLW = (NWU + 255) / 256;
    __shared__ __align__(16) unsigned short sX[2][2][5][33][8];
    __shared__ __align__(16) unsigned short sW[2][2][9][32][8];
    const int tid = threadIdx.x;
    const int lane = tid & 63, wv = tid >> 6;
    const int n = lane & 31, kh = lane >> 5;
    const int x0 = blockIdx.x * 32;
    const int y0q = blockIdx.y * 4;
    const int cog = blockIdx.z;
    const uint4* wU4 = (const uint4*)wsp;

    f32x16 acc[4];
    #pragma unroll
    for (int d = 0; d < 4; ++d) acc[d] = (f32x16)0.0f;

    uint4 vx[NLX], vw[NLW];
    auto LOADS = [&](int ch) {
        #pragma unroll
        for (int i = 0; i < NLX; ++i) {
            int idx = tid + i * 256;
            int sub = idx & 3, hl = sub >> 1, khs = sub & 1;
            int cell = idx >> 2, row = cell / 33, col = cell - row * 33;
            int gy = y0q + row, gx = x0 + col;
            uint4 v = make_uint4(0u, 0u, 0u, 0u);
            if (idx < NXU && gy < HIN && gx < WIN)
                v = *(const uint4*)&xA[(size_t)hl * LIN +
                        ((size_t)(ch * HIN + gy) * WIN + gx) * 16 + khs * 8];
            vx[i] = v;
        }
        #pragma unroll
        for (int i = 0; i < NLW; ++i) {
            int idx = tid + i * 256;
            int idc = (idx < NWU) ? idx : (NWU - 1);
            vw[i] = wU4[(size_t)(cog * CH + ch) * NWU + idc];
        }
    };
    auto WRITE = [&]() {
        #pragma unroll
        for (int i = 0; i < NLX; ++i) {
            int idx = tid + i * 256;
            if (idx < NXU) {
                int sub = idx & 3, hl = sub >> 1, khs = sub & 1;
                int cell = idx >> 2, row = cell / 33, col = cell - row * 33;
                *(uint4*)&sX[hl][khs][row][col][0] = vx[i];
            }
        }
        uint4* dW = (uint4*)&sW[0][0][0][0][0];
        #pragma unroll
        for (int i = 0; i < NLW; ++i) {
            int idx = tid + i * 256;
            if (idx < NWU) dW[idx] = vw[i];
        }
    };

    LOADS(0);
    for (int ch = 0; ch < CH; ++ch) {
        __syncthreads();
        WRITE();
        __syncthreads();
        if (ch + 1 < CH) LOADS(ch + 1);
        short8 xf[2][2][2];     // [hl][dy][dx]
        #pragma unroll
        for (int dy = 0; dy < 2; ++dy)
            #pragma unroll
            for (int dx = 0; dx < 2; ++dx) {
                xf[0][dy][dx] = *(const short8*)&sX[0][kh][wv + dy][n + dx][0];
                xf[1][dy][dx] = *(const short8*)&sX[1][kh][wv + dy][n + dx][0];
            }
        constexpr int SRC[9] = {3, 2, 2, 1, 0, 0, 1, 0, 0};
        constexpr int DST[9] = {3, 2, 3, 1, 0, 1, 3, 2, 3};
        #pragma unroll
        for (int t = 0; t < 9; ++t) {
            short8 wh = *(const short8*)&sW[0][kh][t][n][0];
            short8 wl = *(const short8*)&sW[1][kh][t][n][0];
            const int dy = SRC[t] >> 1, dx = SRC[t] & 1, d = DST[t];
            acc[d] = __builtin_amdgcn_mfma_f32_32x32x16_bf16(wh, xf[0][dy][dx], acc[d], 0, 0, 0);
            acc[d] = __builtin_amdgcn_mfma_f32_32x32x16_bf16(wh, xf[1][dy][dx], acc[d], 0, 0, 0);
            acc[d] = __builtin_amdgcn_mfma_f32_32x32x16_bf16(wl, xf[0][dy][dx], acc[d], 0, 0, 0);
        }
    }
    const int oyb = 2 * (y0q + wv), oxb = 2 * (x0 + n);
    #pragma unroll
    for (int pos = 0; pos < 4; ++pos) {
        const int oy = oyb + (pos >> 1), ox = oxb + (pos & 1);
        #pragma unroll
        for (int grp = 0; grp < 4; ++grp) {
            int co4 = cog * 32 + grp * 8 + kh * 4;
            short4v h4, l4;
            #pragma unroll
            for (int j = 0; j < 4; ++j) {
                float v = fmaxf(acc[pos][grp * 4 + j] + bias[co4 + j], 0.f);
                unsigned short h = f2bf(v);
                h4[j] = (short)h;
                l4[j] = (short)f2bf(v - bf2f(h));
            }
            size_t a = ((size_t)(co4 >> 4) * HO * WO + (size_t)oy * WO + ox) * 16 + (co4 & 15);
            *(short4v*)&outA[a] = h4;
            *(short4v*)&outA[a + LOUT] = l4;
        }
    }
}

// ---------------- final conv (128->3) + tanh, from bf16-hi A-format ----------
__global__ __launch_bounds__(256) void coA_kernel(const unsigned short* __restrict__ xA,
                                                  const float* __restrict__ wO,
                                                  const float* __restrict__ bo,
                                                  float* __restrict__ rec) {
    const int tid = threadIdx.x;
    const int lx = tid & 15, ly = tid >> 4;
    const int tx0 = (blockIdx.x & 15) * 16, ty0 = (blockIdx.x >> 4) * 16;
    const int ox = tx0 + lx, oy = ty0 + ly;
    float a0 = bo[0], a1 = bo[1], a2 = bo[2];
    for (int ch = 0; ch < 8; ++ch) {
        unsigned short cs[9][16];
        #pragma unroll
        for (int t = 0; t < 9; ++t) {
            const int gy = oy - 1 + t / 3, gx = ox - 1 + t % 3;
            uint4 v0 = make_uint4(0u, 0u, 0u, 0u), v1 = make_uint4(0u, 0u, 0u, 0u);
            if (gy >= 0 && gy < 256 && gx >= 0 && gx < 256) {
                const uint4* p = (const uint4*)&xA[((size_t)(ch * 256 + gy) * 256 + gx) * 16];
                v0 = p[0]; v1 = p[1];
            }
            *(uint4*)&cs[t][0] = v0;
            *(uint4*)&cs[t][8] = v1;
        }
        #pragma unroll
        for (int t = 0; t < 9; ++t) {
            const float* w0 = &wO[(0 * 9 + t) * 128 + ch * 16];
            const float* w1 = &wO[(1 * 9 + t) * 128 + ch * 16];
            const float* w2 = &wO[(2 * 9 + t) * 128 + ch * 16];
            #pragma unroll
            for (int j = 0; j < 16; ++j) {
                float v = bf2f(cs[t][j]);
                a0 = fmaf(v, w0[j], a0);
                a1 = fmaf(v, w1[j], a1);
                a2 = fmaf(v, w2[j], a2);
            }
        }
    }
    const int px = oy * 256 + ox;
    rec[px]                = tanhf(a0);
    rec[65536 + px]        = tanhf(a1);
    rec[2 * 65536 + px]    = tanhf(a2);
}

// ---------------------------------------------------------------------------
extern "C" void kernel_launch(void* const* d_in, const int* in_sizes, int n_in,
                              void* d_out, int out_size, void* d_ws, size_t ws_size,
                              hipStream_t stream) {
    const float* x   = (const float*)d_in[0];
    const float* We0 = (const float*)d_in[1];  const float* be0 = (const float*)d_in[2];
    const float* We1 = (const float*)d_in[3];  const float* be1 = (const float*)d_in[4];
    const float* Wi  = (const float*)d_in[5];  const float* bi  = (const float*)d_in[6];
    const float* Wd1 = (const float*)d_in[7];  const float* bd1 = (const float*)d_in[8];
    const float* Wc1 = (const float*)d_in[9];  const float* bc1 = (const float*)d_in[10];
    const float* Wd2 = (const float*)d_in[11]; const float* bd2 = (const float*)d_in[12];
    const float* Wc2 = (const float*)d_in[13]; const float* bc2 = (const float*)d_in[14];
    const float* Wd3 = (const float*)d_in[15]; const float* bd3 = (const float*)d_in[16];
    const float* Wc3 = (const float*)d_in[17]; const float* bc3 = (const float*)d_in[18];
    const float* Wo  = (const float*)d_in[19]; const float* bo  = (const float*)d_in[20];

    float* out    = (float*)d_out;
    float* rec    = out;               // [8,3,256,256]
    float* routed = out + 1572864;     // [8,4,32,32]
    float* grain  = out + 1605632;     // [8,16,16]
    float* ent    = out + 1607680;     // [8,16,16]

    // latent scratch in rec region (dead before first rec write)
    float* latf = out;                 // 32768 floats
    float* latc = out + 32768;         // 8192 floats
    float* thr  = out + 40960;         // 1 float
    // Wc3 split slot in rec[7] tail: written once; last read c3(7); then
    // overwritten by coA(7) (stream-serial).
    unsigned short* slotC3 = (unsigned short*)(out + 1425408);

    // workspace: U activations [0,16.8M); slots [24M,32M); V = [32M,65.6M).
    char* ws8 = (char*)d_ws;
    unsigned short* Uu    = (unsigned short*)ws8;
    unsigned short* Vp    = (unsigned short*)(ws8 + (size_t)32 * 1024 * 1024);
    unsigned short* wspD1 = (unsigned short*)(ws8 + (size_t)24 * 1024 * 1024);
    unsigned short* wspC1 = (unsigned short*)(ws8 + (size_t)26 * 1024 * 1024 + 512 * 1024);
    unsigned short* wspD2 = (unsigned short*)(ws8 + (size_t)29 * 1024 * 1024);
    unsigned short* wspD3 = (unsigned short*)(ws8 + (size_t)30 * 1024 * 1024 + 256 * 1024);
    unsigned short* wspC2 = (unsigned short*)(ws8 + (size_t)31 * 1024 * 1024);
    float*          wspO  = (float*)(ws8 + (size_t)31 * 1024 * 1024 + 768 * 1024);

    // --- entropy / routing path ---
    enc_conv_kernel<<<128, 256, 0, stream>>>(x, We0, be0, latf, 8, 32);
    enc_conv_kernel<<<32, 256, 0, stream>>>(x, We1, be1, latc, 16, 16);
    entropy_kernel<<<2048, 256, 0, stream>>>(x, ent);
    median_kernel<<<1, 1024, 0, stream>>>(ent, thr);
    grain_kernel<<<8, 256, 0, stream>>>(ent, thr, grain);
    route_kernel<<<128, 256, 0, stream>>>(latf, latc, grain, routed);

    // --- weight pre-split: ONCE ---
    wsplit_all_kernel<<<7502, 256, 0, stream>>>(Wd1, Wc1, Wd2, Wc2, Wd3, Wc3, Wo,
                                                wspD1, wspC1, wspD2, wspC2, wspD3, slotC3,
                                                wspO);

    // --- decoder, per batch ---
    for (int b = 0; b < B; ++b) {
        const float* rb = routed + (size_t)b * 4 * 32 * 32;
        float* recb = rec + (size_t)b * 3 * 65536;
        // Wi: routed(fp32) -> h0 A-format hi/lo in U[0,1M)
        conv3x3A<4, 256, 32, 32, 4, 16><<<dim3(16, 4, 1), 256, 0, stream>>>(rb, Wi, bi, Uu);
        // d1: U -> V A (4M)
        deconvM<256, 256, 32, 32><<<dim3(1, 8, 8), 256, 0, stream>>>(Uu, wspD1, bd1, Vp);
        // c1: V -> U A (4M); NCG=1 -> 256 blocks
        convM<256, 256, 64, 64, 1, 1, 1><<<dim3(2, 16, 8), 256, 0, stream>>>(Vp, wspC1, bc1, Uu);
        // d2: U -> V A (8M)
        deconvM<256, 128, 64, 64><<<dim3(2, 16, 4), 256, 0, stream>>>(Uu, wspD2, bd2, Vp);
        // c2: V -> U A (8M); NCG=1 -> 512 blocks
        convM<128, 128, 128, 128, 1, 1, 1><<<dim3(4, 32, 4), 256, 0, stream>>>(Vp, wspC2, bc2, Uu);
        // d3: U -> V A hi/lo (33.6M, fills V)
        deconvM<128, 128, 128, 128><<<dim3(4, 32, 4), 256, 0, stream>>>(Uu, wspD3, bd3, Vp);
        // c3: V -> U A hi-only (16.8M); NCG=2 -> 512 blocks
        convM<128, 128, 256, 256, 2, 2, 2><<<dim3(8, 32, 2), 256, 0, stream>>>(Vp, slotC3, bc3, Uu);
        // co: U(hi A) -> rec fp32 + tanh
        coA_kernel<<<256, 256, 0, stream>>>(Uu, wspO, bo, recb);
    }
}